// Round 10
// baseline (995.676 us; speedup 1.0000x reference)
//
#include <hip/hip_runtime.h>
#include <math.h>

#define B_ 256
#define N_ 200
#define D_ 128
#define H_ 8
#define KD_ 16
#define L_ 3
#define FF_ 512
#define ROWS (B_*N_)          // 51200
#define BND (ROWS*D_)         // 6,553,600

typedef __bf16 bf16x8 __attribute__((ext_vector_type(8)));
typedef float f32x4 __attribute__((ext_vector_type(4)));

__device__ __forceinline__ ushort f2bf(float f) {
  union { float f; unsigned u; } v; v.f = f;
  unsigned r = v.u + 0x7fffu + ((v.u >> 16) & 1u);
  return (ushort)(r >> 16);
}
__device__ __forceinline__ float bf2f(ushort h) {
  union { unsigned u; float f; } v; v.u = ((unsigned)h) << 16; return v.f;
}
__device__ __forceinline__ void split2(float f, ushort& hi, ushort& lo) {
  hi = f2bf(f);
  lo = f2bf(f - bf2f(hi));
}

// ---------------- embed: h = x @ Wemb + bemb -> hp fp32 + hi/lo bf16 ----------------
__global__ __launch_bounds__(256) void embed_kernel(const float* __restrict__ x,
    const float* __restrict__ Wemb, const float* __restrict__ bemb,
    float* __restrict__ hp, ushort* __restrict__ hhi, ushort* __restrict__ hlo)
{
  int i4 = blockIdx.x * 256 + threadIdx.x;   // ROWS*32 float4s
  int r  = i4 >> 5, c4 = i4 & 31;
  float x0 = x[2*r], x1 = x[2*r + 1];
  const float4 w0 = ((const float4*)Wemb)[c4];
  const float4 w1 = ((const float4*)Wemb)[32 + c4];
  const float4 bb = ((const float4*)bemb)[c4];
  float o[4];
  o[0] = fmaf(x0, w0.x, fmaf(x1, w1.x, bb.x));
  o[1] = fmaf(x0, w0.y, fmaf(x1, w1.y, bb.y));
  o[2] = fmaf(x0, w0.z, fmaf(x1, w1.z, bb.z));
  o[3] = fmaf(x0, w0.w, fmaf(x1, w1.w, bb.w));
  float4 of = { o[0], o[1], o[2], o[3] };
  ((float4*)hp)[i4] = of;
  ushort hi[4], lo[4];
#pragma unroll
  for (int k = 0; k < 4; k++) split2(o[k], hi[k], lo[k]);
  uint2 ph, pl;
  ph.x = (uint)hi[0] | ((uint)hi[1] << 16);
  ph.y = (uint)hi[2] | ((uint)hi[3] << 16);
  pl.x = (uint)lo[0] | ((uint)lo[1] << 16);
  pl.y = (uint)lo[2] | ((uint)lo[3] << 16);
  ((uint2*)hhi)[i4] = ph;
  ((uint2*)hlo)[i4] = pl;
}

// ------------- static weight transposes (Wo, W2) -> bf16 hi/lo [N][K] -------------
__global__ __launch_bounds__(256) void t_wo(const float* __restrict__ Wo,
    ushort* __restrict__ dhi, ushort* __restrict__ dlo)
{
  int i = blockIdx.x * 256 + threadIdx.x;     // L*128*128 = 49152 exact
  int l = i / 16384, r = i % 16384;
  int n = r >> 7, k = r & 127;
  int hh = k >> 4, kd = k & 15;
  float w = Wo[l*16384 + hh*2048 + kd*128 + n];
  split2(w, dhi[i], dlo[i]);
}
__global__ __launch_bounds__(256) void t_w2(const float* __restrict__ W2,
    ushort* __restrict__ dhi, ushort* __restrict__ dlo)
{
  int i = blockIdx.x * 256 + threadIdx.x;     // L*128*512 = 196608 exact
  int l = i / 65536, r = i % 65536;
  int d = r >> 9, f = r & 511;
  float w = W2[l*65536 + f*128 + d];
  split2(w, dhi[i], dlo[i]);
}

// ------------- init BN-fold state to identity -------------
__global__ __launch_bounds__(128) void init_scales(float* __restrict__ sc, float* __restrict__ sh)
{
  int c = threadIdx.x;
  sc[c] = 1.f;
  sh[c] = 0.f;
}

// ------------- fold BN into QKV weights (PARALLEL: block=n-row, thread=k) -------------
__global__ __launch_bounds__(128) void fold_qkv(const float* __restrict__ Wq,
    const float* __restrict__ Wk, const float* __restrict__ Wv,
    const float* __restrict__ sc, const float* __restrict__ sh,
    ushort* __restrict__ whi, ushort* __restrict__ wlo, float* __restrict__ bout)
{
  __shared__ float wsum[2];
  int n = blockIdx.x;                     // 0..383
  int k = threadIdx.x;                    // 0..127
  int which = n >> 7, hh = (n >> 4) & 7, kd = n & 15;
  const float* src = (which == 0) ? Wq : (which == 1) ? Wk : Wv;
  float w = src[hh*2048 + k*16 + kd];
  split2(w * sc[k], whi[n*128 + k], wlo[n*128 + k]);   // coalesced writes over k
  float p = sh[k] * w;
#pragma unroll
  for (int d = 1; d < 64; d <<= 1) p += __shfl_xor(p, d);
  if ((k & 63) == 0) wsum[k >> 6] = p;
  __syncthreads();
  if (k == 0) bout[n] = wsum[0] + wsum[1];
}

// ------------- fold BN into W1 (PARALLEL: block=f-row, thread=k) -------------
__global__ __launch_bounds__(128) void fold_w1(const float* __restrict__ W1,
    const float* __restrict__ b1, const float* __restrict__ sc, const float* __restrict__ sh,
    ushort* __restrict__ whi, ushort* __restrict__ wlo, float* __restrict__ bout)
{
  __shared__ float wsum[2];
  int f = blockIdx.x;                     // 0..511
  int k = threadIdx.x;                    // 0..127
  float w = W1[k*512 + f];
  split2(w * sc[k], whi[f*128 + k], wlo[f*128 + k]);
  float p = sh[k] * w;
#pragma unroll
  for (int d = 1; d < 64; d <<= 1) p += __shfl_xor(p, d);
  if ((k & 63) == 0) wsum[k >> 6] = p;
  __syncthreads();
  if (k == 0) bout[f] = b1[f] + wsum[0] + wsum[1];
}

// ---------------- split-bf16 MFMA GEMM: BK=64 XOR-swizzle body + BN-fold epilogue ----------------
template<int K, bool BIAS, bool RELU, bool RESIDBN, bool OUTF32, bool OUTHL, bool STATS>
__global__ __launch_bounds__(256, 2) void gemm_mfma(
    const ushort* __restrict__ Ahi, const ushort* __restrict__ Alo,
    const ushort* __restrict__ Whi, const ushort* __restrict__ Wlo,
    const float* __restrict__ bias,
    const float* __restrict__ residf, const float* __restrict__ rsc, const float* __restrict__ rsh,
    float* __restrict__ Cf, ushort* __restrict__ Chi, ushort* __restrict__ Clo,
    float* __restrict__ psum, float* __restrict__ psq, int Ntot)
{
  __shared__ ushort AhiS[128*64];
  __shared__ ushort AloS[128*64];
  __shared__ ushort BhiS[128*64];
  __shared__ ushort BloS[128*64];
  const int t    = threadIdx.x;
  const int bm   = blockIdx.y * 128;
  const int bn   = blockIdx.x * 128;
  const int lane = t & 63;
  const int w    = t >> 6, wm = w >> 1, wn = w & 1;
  const int quad = lane >> 4, l15 = lane & 15;

  f32x4 acc[4][4];
#pragma unroll
  for (int i = 0; i < 4; i++)
#pragma unroll
    for (int j = 0; j < 4; j++) acc[i][j] = (f32x4){0.f, 0.f, 0.f, 0.f};

  const ushort* AhiB = Ahi + (size_t)bm * K;
  const ushort* AloB = Alo + (size_t)bm * K;
  const ushort* BhiB = Whi + (size_t)bn * K;
  const ushort* BloB = Wlo + (size_t)bn * K;

  for (int k0 = 0; k0 < K; k0 += 64) {
#pragma unroll
    for (int i = 0; i < 4; i++) {
      int idx = i * 256 + t;
      int row = idx >> 3, c = idx & 7;
      int k8  = c ^ (row & 7);
      size_t off = (size_t)row * K + k0 + k8 * 8;
      ((uint4*)AhiS)[idx] = *(const uint4*)(AhiB + off);
      ((uint4*)AloS)[idx] = *(const uint4*)(AloB + off);
      ((uint4*)BhiS)[idx] = *(const uint4*)(BhiB + off);
      ((uint4*)BloS)[idx] = *(const uint4*)(BloB + off);
    }
    __syncthreads();
#pragma unroll
    for (int ks = 0; ks < 2; ks++) {
      bf16x8 ah[4], al[4], bh[4], bl[4];
#pragma unroll
      for (int i = 0; i < 4; i++) {
        int row = wm * 64 + i * 16 + l15;
        int k8  = ks * 4 + quad;
        int ci  = k8 ^ (row & 7);
        ah[i] = ((const bf16x8*)AhiS)[row * 8 + ci];
        al[i] = ((const bf16x8*)AloS)[row * 8 + ci];
        int nrow = wn * 64 + i * 16 + l15;
        int cj   = k8 ^ (nrow & 7);
        bh[i] = ((const bf16x8*)BhiS)[nrow * 8 + cj];
        bl[i] = ((const bf16x8*)BloS)[nrow * 8 + cj];
      }
#pragma unroll
      for (int i = 0; i < 4; i++)
#pragma unroll
        for (int j = 0; j < 4; j++) {
          acc[i][j] = __builtin_amdgcn_mfma_f32_16x16x32_bf16(al[i], bh[j], acc[i][j], 0, 0, 0);
          acc[i][j] = __builtin_amdgcn_mfma_f32_16x16x32_bf16(ah[i], bl[j], acc[i][j], 0, 0, 0);
          acc[i][j] = __builtin_amdgcn_mfma_f32_16x16x32_bf16(ah[i], bh[j], acc[i][j], 0, 0, 0);
        }
    }
    __syncthreads();
  }

  float bv[4], scv[4], shv[4];
#pragma unroll
  for (int j = 0; j < 4; j++) {
    int col = bn + wn*64 + j*16 + l15;
    if (BIAS)    bv[j]  = bias[col];
    if (RESIDBN) { scv[j] = rsc[col]; shv[j] = rsh[col]; }
  }
  float sj[4] = {0.f,0.f,0.f,0.f}, qj[4] = {0.f,0.f,0.f,0.f};
#pragma unroll
  for (int i = 0; i < 4; i++) {
#pragma unroll
    for (int r = 0; r < 4; r++) {
      int row = bm + wm*64 + i*16 + quad*4 + r;
#pragma unroll
      for (int j = 0; j < 4; j++) {
        int col = bn + wn*64 + j*16 + l15;
        float v = acc[i][j][r];
        if (BIAS)    v += bv[j];
        if (RELU)    v = fmaxf(v, 0.f);
        if (RESIDBN) v += fmaf(residf[(size_t)row * Ntot + col], scv[j], shv[j]);
        if (OUTF32)  Cf[(size_t)row * Ntot + col] = v;
        if (OUTHL) {
          ushort hi, lo;
          split2(v, hi, lo);
          Chi[(size_t)row * Ntot + col] = hi;
          Clo[(size_t)row * Ntot + col] = lo;
        }
        if (STATS) { sj[j] += v; qj[j] = fmaf(v, v, qj[j]); }
      }
    }
  }
  if (STATS) {
#pragma unroll
    for (int j = 0; j < 4; j++) {
      sj[j] += __shfl_xor(sj[j], 16); sj[j] += __shfl_xor(sj[j], 32);
      qj[j] += __shfl_xor(qj[j], 16); qj[j] += __shfl_xor(qj[j], 32);
    }
    float* ssum = (float*)AhiS;     // safe: k-loop ended with barrier
    float* ssq  = ssum + 128;
    if (t < 128) { ssum[t] = 0.f; ssq[t] = 0.f; }
    __syncthreads();
    if (quad == 0) {
#pragma unroll
      for (int j = 0; j < 4; j++) {
        int col = wn*64 + j*16 + l15;
        atomicAdd(&ssum[col], sj[j]);
        atomicAdd(&ssq[col],  qj[j]);
      }
    }
    __syncthreads();
    if (t < 128) {
      psum[blockIdx.y * 128 + t] = ssum[t];
      psq [blockIdx.y * 128 + t] = ssq[t];
    }
  }
}

// ---------------- fused attention: scalar, exp2-domain softmax ----------------
// q pre-scaled by (1/sqrt(KD))*log2(e) so p = exp2(s - m) == softmax numerator.
__global__ __launch_bounds__(256) void attn_kernel(const float* __restrict__ qkv,
    ushort* __restrict__ Ohi, ushort* __restrict__ Olo)
{
  __shared__ __align__(16) float Ks[N_][KD_];
  __shared__ __align__(16) float Vs[N_][KD_];
  const int b  = blockIdx.x >> 3;
  const int hh = blockIdx.x & 7;
  const int t  = threadIdx.x;
  const float* basep = qkv + (size_t)b * N_ * 384;
  for (int i = t; i < N_ * 8; i += 256) {
    int n = i >> 3, q4 = i & 7;
    if (q4 < 4)
      ((float4*)&Ks[n][0])[q4]     = *(const float4*)(basep + n*384 + 128 + hh*16 + q4*4);
    else
      ((float4*)&Vs[n][0])[q4 - 4] = *(const float4*)(basep + n*384 + 256 + hh*16 + (q4-4)*4);
  }
  __syncthreads();
  if (t < N_) {
    const float QS = 0.25f * 1.44269504f;   // 1/sqrt(16) * log2(e)
    float q[KD_];
#pragma unroll
    for (int j4 = 0; j4 < 4; j4++) {
      float4 v4 = *(const float4*)(basep + t*384 + hh*16 + j4*4);
      q[j4*4+0] = v4.x * QS; q[j4*4+1] = v4.y * QS;
      q[j4*4+2] = v4.z * QS; q[j4*4+3] = v4.w * QS;
    }
    float m = -1e30f, l = 0.f;
    float o[KD_] = {0.f};
    for (int c0 = 0; c0 < N_; c0 += 40) {
      float s[40];
      float cmax = -1e30f;
#pragma unroll
      for (int j = 0; j < 40; j++) {
        const float4* kr = (const float4*)&Ks[c0 + j][0];
        float4 k0 = kr[0], k1 = kr[1], k2 = kr[2], k3 = kr[3];
        float a = 0.f;
        a = fmaf(q[0],  k0.x, a); a = fmaf(q[1],  k0.y, a);
        a = fmaf(q[2],  k0.z, a); a = fmaf(q[3],  k0.w, a);
        a = fmaf(q[4],  k1.x, a); a = fmaf(q[5],  k1.y, a);
        a = fmaf(q[6],  k1.z, a); a = fmaf(q[7],  k1.w, a);
        a = fmaf(q[8],  k2.x, a); a = fmaf(q[9],  k2.y, a);
        a = fmaf(q[10], k2.z, a); a = fmaf(q[11], k2.w, a);
        a = fmaf(q[12], k3.x, a); a = fmaf(q[13], k3.y, a);
        a = fmaf(q[14], k3.z, a); a = fmaf(q[15], k3.w, a);
        s[j] = a;
        cmax = fmaxf(cmax, a);
      }
      float mn   = fmaxf(m, cmax);
      float corr = exp2f(m - mn);
      l *= corr;
#pragma unroll
      for (int kk = 0; kk < KD_; kk++) o[kk] *= corr;
#pragma unroll
      for (int j = 0; j < 40; j++) {
        float p = exp2f(s[j] - mn);
        l += p;
        const float4* vr = (const float4*)&Vs[c0 + j][0];
        float4 v0 = vr[0], v1 = vr[1], v2 = vr[2], v3 = vr[3];
        o[0]  = fmaf(p, v0.x, o[0]);  o[1]  = fmaf(p, v0.y, o[1]);
        o[2]  = fmaf(p, v0.z, o[2]);  o[3]  = fmaf(p, v0.w, o[3]);
        o[4]  = fmaf(p, v1.x, o[4]);  o[5]  = fmaf(p, v1.y, o[5]);
        o[6]  = fmaf(p, v1.z, o[6]);  o[7]  = fmaf(p, v1.w, o[7]);
        o[8]  = fmaf(p, v2.x, o[8]);  o[9]  = fmaf(p, v2.y, o[9]);
        o[10] = fmaf(p, v2.z, o[10]); o[11] = fmaf(p, v2.w, o[11]);
        o[12] = fmaf(p, v3.x, o[12]); o[13] = fmaf(p, v3.y, o[13]);
        o[14] = fmaf(p, v3.z, o[14]); o[15] = fmaf(p, v3.w, o[15]);
      }
      m = mn;
    }
    float inv = 1.f / l;
    ushort hi[16], lo[16];
#pragma unroll
    for (int kk = 0; kk < KD_; kk++) split2(o[kk] * inv, hi[kk], lo[kk]);
    size_t obase = ((size_t)(b * N_ + t)) * 128 + hh * 16;
    uint4 ph0, ph1, pl0, pl1;
    ph0.x = (uint)hi[0]  | ((uint)hi[1]  << 16); ph0.y = (uint)hi[2]  | ((uint)hi[3]  << 16);
    ph0.z = (uint)hi[4]  | ((uint)hi[5]  << 16); ph0.w = (uint)hi[6]  | ((uint)hi[7]  << 16);
    ph1.x = (uint)hi[8]  | ((uint)hi[9]  << 16); ph1.y = (uint)hi[10] | ((uint)hi[11] << 16);
    ph1.z = (uint)hi[12] | ((uint)hi[13] << 16); ph1.w = (uint)hi[14] | ((uint)hi[15] << 16);
    pl0.x = (uint)lo[0]  | ((uint)lo[1]  << 16); pl0.y = (uint)lo[2]  | ((uint)lo[3]  << 16);
    pl0.z = (uint)lo[4]  | ((uint)lo[5]  << 16); pl0.w = (uint)lo[6]  | ((uint)lo[7]  << 16);
    pl1.x = (uint)lo[8]  | ((uint)lo[9]  << 16); pl1.y = (uint)lo[10] | ((uint)lo[11] << 16);
    pl1.z = (uint)lo[12] | ((uint)lo[13] << 16); pl1.w = (uint)lo[14] | ((uint)lo[15] << 16);
    ((uint4*)(Ohi + obase))[0] = ph0;
    ((uint4*)(Ohi + obase))[1] = ph1;
    ((uint4*)(Olo + obase))[0] = pl0;
    ((uint4*)(Olo + obase))[1] = pl1;
  }
}

// ---------------- BN finalize (reduce 400 partials, unrolled for MLP) ----------------
__global__ __launch_bounds__(128) void bn_finalize(const float* __restrict__ psum,
    const float* __restrict__ psq, const float* __restrict__ g,
    const float* __restrict__ bta, float* __restrict__ scale, float* __restrict__ shift)
{
  int c = threadIdx.x;
  float s = 0.f, q = 0.f;
#pragma unroll 8
  for (int i = 0; i < 400; i++) { s += psum[i*128 + c]; q += psq[i*128 + c]; }
  const float invM = 1.f / 51200.f;
  float m  = s * invM;
  float v  = fmaf(q, invM, -m * m);
  float r  = rsqrtf(v + 1e-5f);
  float sc = r * g[c];
  scale[c] = sc;
  shift[c] = fmaf(-m, sc, bta[c]);
}

// ---------------- final BN apply (in place, fp32) ----------------
__global__ __launch_bounds__(256) void bn_apply_final(float* __restrict__ hp,
    const float* __restrict__ scale, const float* __restrict__ shift)
{
  int i4 = blockIdx.x * 256 + threadIdx.x;   // ROWS*32 exact
  int c4 = i4 & 31;
  float4 v  = ((float4*)hp)[i4];
  float4 sc = ((const float4*)scale)[c4];
  float4 sh = ((const float4*)shift)[c4];
  v.x = fmaf(v.x, sc.x, sh.x);
  v.y = fmaf(v.y, sc.y, sh.y);
  v.z = fmaf(v.z, sc.z, sh.z);
  v.w = fmaf(v.w, sc.w, sh.w);
  ((float4*)hp)[i4] = v;
}

// ---------------- final mean over N ----------------
__global__ __launch_bounds__(128) void mean_kernel(const float* __restrict__ h,
                                                   float* __restrict__ out)
{
  int b = blockIdx.x, d = threadIdx.x;
  const float* p = h + (size_t)b * N_ * D_ + d;
  float s = 0.f;
  for (int n = 0; n < N_; n++) s += p[n * D_];
  out[b * D_ + d] = s * (1.f / N_);
}

extern "C" void kernel_launch(void* const* d_in, const int* in_sizes, int n_in,
                              void* d_out, int out_size, void* d_ws, size_t ws_size,
                              hipStream_t stream)
{
  const float* x    = (const float*)d_in[0];
  const float* Wemb = (const float*)d_in[1];
  const float* bemb = (const float*)d_in[2];
  const float* Wq   = (const float*)d_in[3];
  const float* Wk   = (const float*)d_in[4];
  const float* Wv   = (const float*)d_in[5];
  const float* Wo   = (const float*)d_in[6];
  const float* bn1g = (const float*)d_in[7];
  const float* bn1b = (const float*)d_in[8];
  const float* W1   = (const float*)d_in[9];
  const float* b1   = (const float*)d_in[10];
  const float* W2   = (const float*)d_in[11];
  const float* b2   = (const float*)d_in[12];
  const float* bn2g = (const float*)d_in[13];
  const float* bn2b = (const float*)d_in[14];
  float* out = (float*)d_out;

  // rolling pre-BN residual state hp lives in d_out[0:BND]
  float* hp = out;

  char* wsb = (char*)d_ws;
  ushort* h_hi  = (ushort*)wsb;                     // 13,107,200 B
  ushort* h_lo  = (ushort*)(wsb + 13107200);        // 13,107,200 B
  char*   phase = wsb + 26214400;                   // 104,857,600 B union
  float*  qkv   = (float*)phase;                    //   attn: 78,643,200 B fp32
  ushort* hd_hi = (ushort*)(phase + 78643200);      //   attn: 13,107,200 B
  ushort* hd_lo = (ushort*)(phase + 91750400);      //   attn: 13,107,200 B
  ushort* hid_hi = (ushort*)phase;                  //   ffn: 52,428,800 B
  ushort* hid_lo = (ushort*)(phase + 52428800);     //   ffn: 52,428,800 B
  char*   wp    = wsb + 131072000;
  ushort* woT_hi  = (ushort*)wp;                    // 98,304 B
  ushort* woT_lo  = (ushort*)(wp + 98304);          // 98,304 B
  ushort* w2T_hi  = (ushort*)(wp + 196608);         // 393,216 B
  ushort* w2T_lo  = (ushort*)(wp + 589824);         // 393,216 B
  ushort* fqkv_hi = (ushort*)(wp + 983040);         // 98,304 B
  ushort* fqkv_lo = (ushort*)(wp + 1081344);        // 98,304 B
  ushort* fw1_hi  = (ushort*)(wp + 1179648);        // 131,072 B
  ushort* fw1_lo  = (ushort*)(wp + 1310720);        // 131,072 B
  float*  fqkv_b  = (float*)(wp + 1441792);         // 1,536 B
  float*  fw1_b   = (float*)(wp + 1443328);         // 2,048 B
  float*  psum    = (float*)(wp + 1445376);         // 204,800 B
  float*  psq     = (float*)(wp + 1650176);         // 204,800 B
  float*  sc_a    = (float*)(wp + 1854976);
  float*  sh_a    = (float*)(wp + 1855488);
  float*  sc_b    = (float*)(wp + 1856000);
  float*  sh_b    = (float*)(wp + 1856512);

  embed_kernel<<<6400, 256, 0, stream>>>(x, Wemb, bemb, hp, h_hi, h_lo);
  t_wo<<<192, 256, 0, stream>>>(Wo, woT_hi, woT_lo);
  t_w2<<<768, 256, 0, stream>>>(W2, w2T_hi, w2T_lo);
  init_scales<<<1, 128, 0, stream>>>(sc_b, sh_b);

  for (int l = 0; l < L_; l++) {
    // fold BN(prev layer / identity) into QKV weights (parallel, coalesced)
    fold_qkv<<<384, 128, 0, stream>>>(Wq + l*16384, Wk + l*16384, Wv + l*16384,
                                      sc_b, sh_b, fqkv_hi, fqkv_lo, fqkv_b);
    // QKV projection (consumes pre-BN h hi/lo + folded weights) -> qkv fp32
    gemm_mfma<128, true, false, false, true, false, false><<<dim3(3, 400), 256, 0, stream>>>(
        h_hi, h_lo, fqkv_hi, fqkv_lo, fqkv_b, nullptr, nullptr, nullptr,
        qkv, nullptr, nullptr, nullptr, nullptr, 384);
    // attention -> heads hi/lo
    attn_kernel<<<B_ * H_, 256, 0, stream>>>(qkv, hd_hi, hd_lo);
    // out-proj + BN-folded residual -> hp (h1_pre) fp32 + hi/lo + BN1 stats
    gemm_mfma<128, false, false, true, true, true, true><<<dim3(1, 400), 256, 0, stream>>>(
        hd_hi, hd_lo, woT_hi + l*16384, woT_lo + l*16384, nullptr, hp, sc_b, sh_b,
        hp, h_hi, h_lo, psum, psq, 128);
    bn_finalize<<<1, 128, 0, stream>>>(psum, psq, bn1g + l*128, bn1b + l*128, sc_a, sh_a);
    // fold BN1 into W1 (parallel, coalesced)
    fold_w1<<<512, 128, 0, stream>>>(W1 + l*65536, b1 + l*512, sc_a, sh_a, fw1_hi, fw1_lo, fw1_b);
    // FFN1 + folded bias + relu -> hidden hi/lo
    gemm_mfma<128, true, true, false, false, true, false><<<dim3(4, 400), 256, 0, stream>>>(
        h_hi, h_lo, fw1_hi, fw1_lo, fw1_b, nullptr, nullptr, nullptr,
        nullptr, hid_hi, hid_lo, nullptr, nullptr, 512);
    // FFN2 + bias + BN1-folded residual -> hp (h2_pre) fp32 + hi/lo + BN2 stats
    gemm_mfma<512, true, false, true, true, true, true><<<dim3(1, 400), 256, 0, stream>>>(
        hid_hi, hid_lo, w2T_hi + l*65536, w2T_lo + l*65536, b2 + l*128, hp, sc_a, sh_a,
        hp, h_hi, h_lo, psum, psq, 128);
    bn_finalize<<<1, 128, 0, stream>>>(psum, psq, bn2g + l*128, bn2b + l*128, sc_b, sh_b);
  }

  bn_apply_final<<<6400, 256, 0, stream>>>(hp, sc_b, sh_b);
  mean_kernel<<<B_, 128, 0, stream>>>(hp, out + BND);
}

// Round 11
// 903.138 us; speedup vs baseline: 1.1025x; 1.1025x over previous
//
#include <hip/hip_runtime.h>
#include <math.h>

#define B_ 256
#define N_ 200
#define D_ 128
#define H_ 8
#define KD_ 16
#define L_ 3
#define FF_ 512
#define ROWS (B_*N_)          // 51200
#define BND (ROWS*D_)         // 6,553,600

typedef __bf16 bf16x8 __attribute__((ext_vector_type(8)));
typedef float f32x4 __attribute__((ext_vector_type(4)));
typedef _Float16 h16x2 __attribute__((ext_vector_type(2)));

__device__ __forceinline__ ushort f2bf(float f) {
  union { float f; unsigned u; } v; v.f = f;
  unsigned r = v.u + 0x7fffu + ((v.u >> 16) & 1u);
  return (ushort)(r >> 16);
}
__device__ __forceinline__ float bf2f(ushort h) {
  union { unsigned u; float f; } v; v.u = ((unsigned)h) << 16; return v.f;
}
__device__ __forceinline__ void split2(float f, ushort& hi, ushort& lo) {
  hi = f2bf(f);
  lo = f2bf(f - bf2f(hi));
}

// ---------------- embed: h = x @ Wemb + bemb -> hp fp32 + hi/lo bf16 ----------------
__global__ __launch_bounds__(256) void embed_kernel(const float* __restrict__ x,
    const float* __restrict__ Wemb, const float* __restrict__ bemb,
    float* __restrict__ hp, ushort* __restrict__ hhi, ushort* __restrict__ hlo)
{
  int i4 = blockIdx.x * 256 + threadIdx.x;   // ROWS*32 float4s
  int r  = i4 >> 5, c4 = i4 & 31;
  float x0 = x[2*r], x1 = x[2*r + 1];
  const float4 w0 = ((const float4*)Wemb)[c4];
  const float4 w1 = ((const float4*)Wemb)[32 + c4];
  const float4 bb = ((const float4*)bemb)[c4];
  float o[4];
  o[0] = fmaf(x0, w0.x, fmaf(x1, w1.x, bb.x));
  o[1] = fmaf(x0, w0.y, fmaf(x1, w1.y, bb.y));
  o[2] = fmaf(x0, w0.z, fmaf(x1, w1.z, bb.z));
  o[3] = fmaf(x0, w0.w, fmaf(x1, w1.w, bb.w));
  float4 of = { o[0], o[1], o[2], o[3] };
  ((float4*)hp)[i4] = of;
  ushort hi[4], lo[4];
#pragma unroll
  for (int k = 0; k < 4; k++) split2(o[k], hi[k], lo[k]);
  uint2 ph, pl;
  ph.x = (uint)hi[0] | ((uint)hi[1] << 16);
  ph.y = (uint)hi[2] | ((uint)hi[3] << 16);
  pl.x = (uint)lo[0] | ((uint)lo[1] << 16);
  pl.y = (uint)lo[2] | ((uint)lo[3] << 16);
  ((uint2*)hhi)[i4] = ph;
  ((uint2*)hlo)[i4] = pl;
}

// ------------- static weight transposes (Wo, W2) -> bf16 hi/lo [N][K] -------------
__global__ __launch_bounds__(256) void t_wo(const float* __restrict__ Wo,
    ushort* __restrict__ dhi, ushort* __restrict__ dlo)
{
  int i = blockIdx.x * 256 + threadIdx.x;     // L*128*128 = 49152 exact
  int l = i / 16384, r = i % 16384;
  int n = r >> 7, k = r & 127;
  int hh = k >> 4, kd = k & 15;
  float w = Wo[l*16384 + hh*2048 + kd*128 + n];
  split2(w, dhi[i], dlo[i]);
}
__global__ __launch_bounds__(256) void t_w2(const float* __restrict__ W2,
    ushort* __restrict__ dhi, ushort* __restrict__ dlo)
{
  int i = blockIdx.x * 256 + threadIdx.x;     // L*128*512 = 196608 exact
  int l = i / 65536, r = i % 65536;
  int d = r >> 9, f = r & 511;
  float w = W2[l*65536 + f*128 + d];
  split2(w, dhi[i], dlo[i]);
}

// ------------- init BN-fold state to identity -------------
__global__ __launch_bounds__(128) void init_scales(float* __restrict__ sc, float* __restrict__ sh)
{
  int c = threadIdx.x;
  sc[c] = 1.f;
  sh[c] = 0.f;
}

// ------------- fold BN into QKV weights (PARALLEL: block=n-row, thread=k) -------------
__global__ __launch_bounds__(128) void fold_qkv(const float* __restrict__ Wq,
    const float* __restrict__ Wk, const float* __restrict__ Wv,
    const float* __restrict__ sc, const float* __restrict__ sh,
    ushort* __restrict__ whi, ushort* __restrict__ wlo, float* __restrict__ bout)
{
  __shared__ float wsum[2];
  int n = blockIdx.x;                     // 0..383
  int k = threadIdx.x;                    // 0..127
  int which = n >> 7, hh = (n >> 4) & 7, kd = n & 15;
  const float* src = (which == 0) ? Wq : (which == 1) ? Wk : Wv;
  float w = src[hh*2048 + k*16 + kd];
  split2(w * sc[k], whi[n*128 + k], wlo[n*128 + k]);   // coalesced writes over k
  float p = sh[k] * w;
#pragma unroll
  for (int d = 1; d < 64; d <<= 1) p += __shfl_xor(p, d);
  if ((k & 63) == 0) wsum[k >> 6] = p;
  __syncthreads();
  if (k == 0) bout[n] = wsum[0] + wsum[1];
}

// ------------- fold BN into W1 (PARALLEL: block=f-row, thread=k) -------------
__global__ __launch_bounds__(128) void fold_w1(const float* __restrict__ W1,
    const float* __restrict__ b1, const float* __restrict__ sc, const float* __restrict__ sh,
    ushort* __restrict__ whi, ushort* __restrict__ wlo, float* __restrict__ bout)
{
  __shared__ float wsum[2];
  int f = blockIdx.x;                     // 0..511
  int k = threadIdx.x;                    // 0..127
  float w = W1[k*512 + f];
  split2(w * sc[k], whi[f*128 + k], wlo[f*128 + k]);
  float p = sh[k] * w;
#pragma unroll
  for (int d = 1; d < 64; d <<= 1) p += __shfl_xor(p, d);
  if ((k & 63) == 0) wsum[k >> 6] = p;
  __syncthreads();
  if (k == 0) bout[f] = b1[f] + wsum[0] + wsum[1];
}

// ---------------- split-bf16 MFMA GEMM: BK=64 XOR-swizzle body + BN-fold epilogue ----------------
template<int K, bool BIAS, bool RELU, bool RESIDBN, bool OUTF32, bool OUTHL, bool STATS>
__global__ __launch_bounds__(256, 2) void gemm_mfma(
    const ushort* __restrict__ Ahi, const ushort* __restrict__ Alo,
    const ushort* __restrict__ Whi, const ushort* __restrict__ Wlo,
    const float* __restrict__ bias,
    const float* __restrict__ residf, const float* __restrict__ rsc, const float* __restrict__ rsh,
    float* __restrict__ Cf, ushort* __restrict__ Chi, ushort* __restrict__ Clo,
    float* __restrict__ psum, float* __restrict__ psq, int Ntot)
{
  __shared__ ushort AhiS[128*64];
  __shared__ ushort AloS[128*64];
  __shared__ ushort BhiS[128*64];
  __shared__ ushort BloS[128*64];
  const int t    = threadIdx.x;
  const int bm   = blockIdx.y * 128;
  const int bn   = blockIdx.x * 128;
  const int lane = t & 63;
  const int w    = t >> 6, wm = w >> 1, wn = w & 1;
  const int quad = lane >> 4, l15 = lane & 15;

  f32x4 acc[4][4];
#pragma unroll
  for (int i = 0; i < 4; i++)
#pragma unroll
    for (int j = 0; j < 4; j++) acc[i][j] = (f32x4){0.f, 0.f, 0.f, 0.f};

  const ushort* AhiB = Ahi + (size_t)bm * K;
  const ushort* AloB = Alo + (size_t)bm * K;
  const ushort* BhiB = Whi + (size_t)bn * K;
  const ushort* BloB = Wlo + (size_t)bn * K;

  for (int k0 = 0; k0 < K; k0 += 64) {
#pragma unroll
    for (int i = 0; i < 4; i++) {
      int idx = i * 256 + t;
      int row = idx >> 3, c = idx & 7;
      int k8  = c ^ (row & 7);
      size_t off = (size_t)row * K + k0 + k8 * 8;
      ((uint4*)AhiS)[idx] = *(const uint4*)(AhiB + off);
      ((uint4*)AloS)[idx] = *(const uint4*)(AloB + off);
      ((uint4*)BhiS)[idx] = *(const uint4*)(BhiB + off);
      ((uint4*)BloS)[idx] = *(const uint4*)(BloB + off);
    }
    __syncthreads();
#pragma unroll
    for (int ks = 0; ks < 2; ks++) {
      bf16x8 ah[4], al[4], bh[4], bl[4];
#pragma unroll
      for (int i = 0; i < 4; i++) {
        int row = wm * 64 + i * 16 + l15;
        int k8  = ks * 4 + quad;
        int ci  = k8 ^ (row & 7);
        ah[i] = ((const bf16x8*)AhiS)[row * 8 + ci];
        al[i] = ((const bf16x8*)AloS)[row * 8 + ci];
        int nrow = wn * 64 + i * 16 + l15;
        int cj   = k8 ^ (nrow & 7);
        bh[i] = ((const bf16x8*)BhiS)[nrow * 8 + cj];
        bl[i] = ((const bf16x8*)BloS)[nrow * 8 + cj];
      }
#pragma unroll
      for (int i = 0; i < 4; i++)
#pragma unroll
        for (int j = 0; j < 4; j++) {
          acc[i][j] = __builtin_amdgcn_mfma_f32_16x16x32_bf16(al[i], bh[j], acc[i][j], 0, 0, 0);
          acc[i][j] = __builtin_amdgcn_mfma_f32_16x16x32_bf16(ah[i], bl[j], acc[i][j], 0, 0, 0);
          acc[i][j] = __builtin_amdgcn_mfma_f32_16x16x32_bf16(ah[i], bh[j], acc[i][j], 0, 0, 0);
        }
    }
    __syncthreads();
  }

  float bv[4], scv[4], shv[4];
#pragma unroll
  for (int j = 0; j < 4; j++) {
    int col = bn + wn*64 + j*16 + l15;
    if (BIAS)    bv[j]  = bias[col];
    if (RESIDBN) { scv[j] = rsc[col]; shv[j] = rsh[col]; }
  }
  float sj[4] = {0.f,0.f,0.f,0.f}, qj[4] = {0.f,0.f,0.f,0.f};
#pragma unroll
  for (int i = 0; i < 4; i++) {
#pragma unroll
    for (int r = 0; r < 4; r++) {
      int row = bm + wm*64 + i*16 + quad*4 + r;
#pragma unroll
      for (int j = 0; j < 4; j++) {
        int col = bn + wn*64 + j*16 + l15;
        float v = acc[i][j][r];
        if (BIAS)    v += bv[j];
        if (RELU)    v = fmaxf(v, 0.f);
        if (RESIDBN) v += fmaf(residf[(size_t)row * Ntot + col], scv[j], shv[j]);
        if (OUTF32)  Cf[(size_t)row * Ntot + col] = v;
        if (OUTHL) {
          ushort hi, lo;
          split2(v, hi, lo);
          Chi[(size_t)row * Ntot + col] = hi;
          Clo[(size_t)row * Ntot + col] = lo;
        }
        if (STATS) { sj[j] += v; qj[j] = fmaf(v, v, qj[j]); }
      }
    }
  }
  if (STATS) {
#pragma unroll
    for (int j = 0; j < 4; j++) {
      sj[j] += __shfl_xor(sj[j], 16); sj[j] += __shfl_xor(sj[j], 32);
      qj[j] += __shfl_xor(qj[j], 16); qj[j] += __shfl_xor(qj[j], 32);
    }
    float* ssum = (float*)AhiS;     // safe: k-loop ended with barrier
    float* ssq  = ssum + 128;
    if (t < 128) { ssum[t] = 0.f; ssq[t] = 0.f; }
    __syncthreads();
    if (quad == 0) {
#pragma unroll
      for (int j = 0; j < 4; j++) {
        int col = wn*64 + j*16 + l15;
        atomicAdd(&ssum[col], sj[j]);
        atomicAdd(&ssq[col],  qj[j]);
      }
    }
    __syncthreads();
    if (t < 128) {
      psum[blockIdx.y * 128 + t] = ssum[t];
      psq [blockIdx.y * 128 + t] = ssq[t];
    }
  }
}

// ---------------- fused attention: fp16-dot2 scores, fp32 softmax/PV ----------------
// K staged in LDS as fp16 pairs; q converted to fp16 with 1/sqrt(KD)=0.25 (exact pow2)
// folded in. Scores via v_dot2_f32_f16 (fp32 accumulate). V/PV stay fp32 (R8 path).
__global__ __launch_bounds__(256) void attn_kernel(const float* __restrict__ qkv,
    ushort* __restrict__ Ohi, ushort* __restrict__ Olo)
{
  __shared__ __align__(16) h16x2 Ksh[N_][8];           // 16 fp16 per key
  __shared__ __align__(16) float Vs[N_][KD_];
  const int b  = blockIdx.x >> 3;
  const int hh = blockIdx.x & 7;
  const int t  = threadIdx.x;
  const float* basep = qkv + (size_t)b * N_ * 384;
  for (int i = t; i < N_ * 8; i += 256) {
    int n = i >> 3, q4 = i & 7;
    if (q4 < 4) {
      float4 v = *(const float4*)(basep + n*384 + 128 + hh*16 + q4*4);
      h16x2 a = { (_Float16)v.x, (_Float16)v.y };
      h16x2 c = { (_Float16)v.z, (_Float16)v.w };
      Ksh[n][q4*2]     = a;
      Ksh[n][q4*2 + 1] = c;
    } else {
      ((float4*)&Vs[n][0])[q4 - 4] = *(const float4*)(basep + n*384 + 256 + hh*16 + (q4-4)*4);
    }
  }
  __syncthreads();
  if (t < N_) {
    h16x2 qh[8];
#pragma unroll
    for (int j4 = 0; j4 < 4; j4++) {
      float4 v4 = *(const float4*)(basep + t*384 + hh*16 + j4*4);
      h16x2 a = { (_Float16)(v4.x * 0.25f), (_Float16)(v4.y * 0.25f) };
      h16x2 c = { (_Float16)(v4.z * 0.25f), (_Float16)(v4.w * 0.25f) };
      qh[j4*2]     = a;
      qh[j4*2 + 1] = c;
    }
    float m = -1e30f, l = 0.f;
    float o[KD_] = {0.f};
    for (int c0 = 0; c0 < N_; c0 += 40) {
      float s[40];
      float cmax = -1e30f;
#pragma unroll
      for (int j = 0; j < 40; j++) {
        const h16x2* kr = &Ksh[c0 + j][0];
        float a = 0.f;
#pragma unroll
        for (int e = 0; e < 8; e++)
          a = __builtin_amdgcn_fdot2(qh[e], kr[e], a, false);
        s[j] = a;
        cmax = fmaxf(cmax, a);
      }
      float mn   = fmaxf(m, cmax);
      float corr = __expf(m - mn);
      l *= corr;
#pragma unroll
      for (int kk = 0; kk < KD_; kk++) o[kk] *= corr;
#pragma unroll
      for (int j = 0; j < 40; j++) {
        float p = __expf(s[j] - mn);
        l += p;
        const float4* vr = (const float4*)&Vs[c0 + j][0];
        float4 v0 = vr[0], v1 = vr[1], v2 = vr[2], v3 = vr[3];
        o[0]  = fmaf(p, v0.x, o[0]);  o[1]  = fmaf(p, v0.y, o[1]);
        o[2]  = fmaf(p, v0.z, o[2]);  o[3]  = fmaf(p, v0.w, o[3]);
        o[4]  = fmaf(p, v1.x, o[4]);  o[5]  = fmaf(p, v1.y, o[5]);
        o[6]  = fmaf(p, v1.z, o[6]);  o[7]  = fmaf(p, v1.w, o[7]);
        o[8]  = fmaf(p, v2.x, o[8]);  o[9]  = fmaf(p, v2.y, o[9]);
        o[10] = fmaf(p, v2.z, o[10]); o[11] = fmaf(p, v2.w, o[11]);
        o[12] = fmaf(p, v3.x, o[12]); o[13] = fmaf(p, v3.y, o[13]);
        o[14] = fmaf(p, v3.z, o[14]); o[15] = fmaf(p, v3.w, o[15]);
      }
      m = mn;
    }
    float inv = 1.f / l;
    ushort hi[16], lo[16];
#pragma unroll
    for (int kk = 0; kk < KD_; kk++) split2(o[kk] * inv, hi[kk], lo[kk]);
    size_t obase = ((size_t)(b * N_ + t)) * 128 + hh * 16;
    uint4 ph0, ph1, pl0, pl1;
    ph0.x = (uint)hi[0]  | ((uint)hi[1]  << 16); ph0.y = (uint)hi[2]  | ((uint)hi[3]  << 16);
    ph0.z = (uint)hi[4]  | ((uint)hi[5]  << 16); ph0.w = (uint)hi[6]  | ((uint)hi[7]  << 16);
    ph1.x = (uint)hi[8]  | ((uint)hi[9]  << 16); ph1.y = (uint)hi[10] | ((uint)hi[11] << 16);
    ph1.z = (uint)hi[12] | ((uint)hi[13] << 16); ph1.w = (uint)hi[14] | ((uint)hi[15] << 16);
    pl0.x = (uint)lo[0]  | ((uint)lo[1]  << 16); pl0.y = (uint)lo[2]  | ((uint)lo[3]  << 16);
    pl0.z = (uint)lo[4]  | ((uint)lo[5]  << 16); pl0.w = (uint)lo[6]  | ((uint)lo[7]  << 16);
    pl1.x = (uint)lo[8]  | ((uint)lo[9]  << 16); pl1.y = (uint)lo[10] | ((uint)lo[11] << 16);
    pl1.z = (uint)lo[12] | ((uint)lo[13] << 16); pl1.w = (uint)lo[14] | ((uint)lo[15] << 16);
    ((uint4*)(Ohi + obase))[0] = ph0;
    ((uint4*)(Ohi + obase))[1] = ph1;
    ((uint4*)(Olo + obase))[0] = pl0;
    ((uint4*)(Olo + obase))[1] = pl1;
  }
}

// ---------------- BN finalize (reduce 400 partials) ----------------
__global__ __launch_bounds__(128) void bn_finalize(const float* __restrict__ psum,
    const float* __restrict__ psq, const float* __restrict__ g,
    const float* __restrict__ bta, float* __restrict__ scale, float* __restrict__ shift)
{
  int c = threadIdx.x;
  float s = 0.f, q = 0.f;
  for (int i = 0; i < 400; i++) { s += psum[i*128 + c]; q += psq[i*128 + c]; }
  const float invM = 1.f / 51200.f;
  float m  = s * invM;
  float v  = fmaf(q, invM, -m * m);
  float r  = rsqrtf(v + 1e-5f);
  float sc = r * g[c];
  scale[c] = sc;
  shift[c] = fmaf(-m, sc, bta[c]);
}

// ---------------- final BN apply (in place, fp32) ----------------
__global__ __launch_bounds__(256) void bn_apply_final(float* __restrict__ hp,
    const float* __restrict__ scale, const float* __restrict__ shift)
{
  int i4 = blockIdx.x * 256 + threadIdx.x;   // ROWS*32 exact
  int c4 = i4 & 31;
  float4 v  = ((float4*)hp)[i4];
  float4 sc = ((const float4*)scale)[c4];
  float4 sh = ((const float4*)shift)[c4];
  v.x = fmaf(v.x, sc.x, sh.x);
  v.y = fmaf(v.y, sc.y, sh.y);
  v.z = fmaf(v.z, sc.z, sh.z);
  v.w = fmaf(v.w, sc.w, sh.w);
  ((float4*)hp)[i4] = v;
}

// ---------------- final mean over N ----------------
__global__ __launch_bounds__(128) void mean_kernel(const float* __restrict__ h,
                                                   float* __restrict__ out)
{
  int b = blockIdx.x, d = threadIdx.x;
  const float* p = h + (size_t)b * N_ * D_ + d;
  float s = 0.f;
  for (int n = 0; n < N_; n++) s += p[n * D_];
  out[b * D_ + d] = s * (1.f / N_);
}

extern "C" void kernel_launch(void* const* d_in, const int* in_sizes, int n_in,
                              void* d_out, int out_size, void* d_ws, size_t ws_size,
                              hipStream_t stream)
{
  const float* x    = (const float*)d_in[0];
  const float* Wemb = (const float*)d_in[1];
  const float* bemb = (const float*)d_in[2];
  const float* Wq   = (const float*)d_in[3];
  const float* Wk   = (const float*)d_in[4];
  const float* Wv   = (const float*)d_in[5];
  const float* Wo   = (const float*)d_in[6];
  const float* bn1g = (const float*)d_in[7];
  const float* bn1b = (const float*)d_in[8];
  const float* W1   = (const float*)d_in[9];
  const float* b1   = (const float*)d_in[10];
  const float* W2   = (const float*)d_in[11];
  const float* b2   = (const float*)d_in[12];
  const float* bn2g = (const float*)d_in[13];
  const float* bn2b = (const float*)d_in[14];
  float* out = (float*)d_out;

  // rolling pre-BN residual state hp lives in d_out[0:BND]
  float* hp = out;

  char* wsb = (char*)d_ws;
  ushort* h_hi  = (ushort*)wsb;                     // 13,107,200 B
  ushort* h_lo  = (ushort*)(wsb + 13107200);        // 13,107,200 B
  char*   phase = wsb + 26214400;                   // 104,857,600 B union
  float*  qkv   = (float*)phase;                    //   attn: 78,643,200 B fp32
  ushort* hd_hi = (ushort*)(phase + 78643200);      //   attn: 13,107,200 B
  ushort* hd_lo = (ushort*)(phase + 91750400);      //   attn: 13,107,200 B
  ushort* hid_hi = (ushort*)phase;                  //   ffn: 52,428,800 B
  ushort* hid_lo = (ushort*)(phase + 52428800);     //   ffn: 52,428,800 B
  char*   wp    = wsb + 131072000;
  ushort* woT_hi  = (ushort*)wp;                    // 98,304 B
  ushort* woT_lo  = (ushort*)(wp + 98304);          // 98,304 B
  ushort* w2T_hi  = (ushort*)(wp + 196608);         // 393,216 B
  ushort* w2T_lo  = (ushort*)(wp + 589824);         // 393,216 B
  ushort* fqkv_hi = (ushort*)(wp + 983040);         // 98,304 B
  ushort* fqkv_lo = (ushort*)(wp + 1081344);        // 98,304 B
  ushort* fw1_hi  = (ushort*)(wp + 1179648);        // 131,072 B
  ushort* fw1_lo  = (ushort*)(wp + 1310720);        // 131,072 B
  float*  fqkv_b  = (float*)(wp + 1441792);         // 1,536 B
  float*  fw1_b   = (float*)(wp + 1443328);         // 2,048 B
  float*  psum    = (float*)(wp + 1445376);         // 204,800 B
  float*  psq     = (float*)(wp + 1650176);         // 204,800 B
  float*  sc_a    = (float*)(wp + 1854976);
  float*  sh_a    = (float*)(wp + 1855488);
  float*  sc_b    = (float*)(wp + 1856000);
  float*  sh_b    = (float*)(wp + 1856512);

  embed_kernel<<<6400, 256, 0, stream>>>(x, Wemb, bemb, hp, h_hi, h_lo);
  t_wo<<<192, 256, 0, stream>>>(Wo, woT_hi, woT_lo);
  t_w2<<<768, 256, 0, stream>>>(W2, w2T_hi, w2T_lo);
  init_scales<<<1, 128, 0, stream>>>(sc_b, sh_b);

  for (int l = 0; l < L_; l++) {
    // fold BN(prev layer / identity) into QKV weights (parallel, coalesced)
    fold_qkv<<<384, 128, 0, stream>>>(Wq + l*16384, Wk + l*16384, Wv + l*16384,
                                      sc_b, sh_b, fqkv_hi, fqkv_lo, fqkv_b);
    // QKV projection (consumes pre-BN h hi/lo + folded weights) -> qkv fp32
    gemm_mfma<128, true, false, false, true, false, false><<<dim3(3, 400), 256, 0, stream>>>(
        h_hi, h_lo, fqkv_hi, fqkv_lo, fqkv_b, nullptr, nullptr, nullptr,
        qkv, nullptr, nullptr, nullptr, nullptr, 384);
    // attention -> heads hi/lo
    attn_kernel<<<B_ * H_, 256, 0, stream>>>(qkv, hd_hi, hd_lo);
    // out-proj + BN-folded residual -> hp (h1_pre) fp32 + hi/lo + BN1 stats
    gemm_mfma<128, false, false, true, true, true, true><<<dim3(1, 400), 256, 0, stream>>>(
        hd_hi, hd_lo, woT_hi + l*16384, woT_lo + l*16384, nullptr, hp, sc_b, sh_b,
        hp, h_hi, h_lo, psum, psq, 128);
    bn_finalize<<<1, 128, 0, stream>>>(psum, psq, bn1g + l*128, bn1b + l*128, sc_a, sh_a);
    // fold BN1 into W1 (parallel, coalesced)
    fold_w1<<<512, 128, 0, stream>>>(W1 + l*65536, b1 + l*512, sc_a, sh_a, fw1_hi, fw1_lo, fw1_b);
    // FFN1 + folded bias + relu -> hidden hi/lo
    gemm_mfma<128, true, true, false, false, true, false><<<dim3(4, 400), 256, 0, stream>>>(
        h_hi, h_lo, fw1_hi, fw1_lo, fw1_b, nullptr, nullptr, nullptr,
        nullptr, hid_hi, hid_lo, nullptr, nullptr, 512);
    // FFN2 + bias + BN1-folded residual -> hp (h2_pre) fp32 + hi/lo + BN2 stats
    gemm_mfma<512, true, false, true, true, true, true><<<dim3(1, 400), 256, 0, stream>>>(
        hid_hi, hid_lo, w2T_hi + l*65536, w2T_lo + l*65536, b2 + l*128, hp, sc_a, sh_a,
        hp, h_hi, h_lo, psum, psq, 128);
    bn_finalize<<<1, 128, 0, stream>>>(psum, psq, bn2g + l*128, bn2b + l*128, sc_b, sh_b);
  }

  bn_apply_final<<<6400, 256, 0, stream>>>(hp, sc_b, sh_b);
  mean_kernel<<<B_, 128, 0, stream>>>(hp, out + BND);
}

// Round 12
// 873.194 us; speedup vs baseline: 1.1403x; 1.0343x over previous
//
#include <hip/hip_runtime.h>
#include <math.h>

#define B_ 256
#define N_ 200
#define D_ 128
#define H_ 8
#define KD_ 16
#define L_ 3
#define FF_ 512
#define ROWS (B_*N_)          // 51200
#define BND (ROWS*D_)         // 6,553,600

typedef __bf16 bf16x8 __attribute__((ext_vector_type(8)));
typedef float f32x4 __attribute__((ext_vector_type(4)));
typedef _Float16 h16x2 __attribute__((ext_vector_type(2)));

__device__ __forceinline__ ushort f2bf(float f) {
  union { float f; unsigned u; } v; v.f = f;
  unsigned r = v.u + 0x7fffu + ((v.u >> 16) & 1u);
  return (ushort)(r >> 16);
}
__device__ __forceinline__ float bf2f(ushort h) {
  union { unsigned u; float f; } v; v.u = ((unsigned)h) << 16; return v.f;
}
__device__ __forceinline__ void split2(float f, ushort& hi, ushort& lo) {
  hi = f2bf(f);
  lo = f2bf(f - bf2f(hi));
}

// ---------------- embed: h = x @ Wemb + bemb -> hp fp32 + hi/lo bf16 ----------------
__global__ __launch_bounds__(256) void embed_kernel(const float* __restrict__ x,
    const float* __restrict__ Wemb, const float* __restrict__ bemb,
    float* __restrict__ hp, ushort* __restrict__ hhi, ushort* __restrict__ hlo)
{
  int i4 = blockIdx.x * 256 + threadIdx.x;   // ROWS*32 float4s
  int r  = i4 >> 5, c4 = i4 & 31;
  float x0 = x[2*r], x1 = x[2*r + 1];
  const float4 w0 = ((const float4*)Wemb)[c4];
  const float4 w1 = ((const float4*)Wemb)[32 + c4];
  const float4 bb = ((const float4*)bemb)[c4];
  float o[4];
  o[0] = fmaf(x0, w0.x, fmaf(x1, w1.x, bb.x));
  o[1] = fmaf(x0, w0.y, fmaf(x1, w1.y, bb.y));
  o[2] = fmaf(x0, w0.z, fmaf(x1, w1.z, bb.z));
  o[3] = fmaf(x0, w0.w, fmaf(x1, w1.w, bb.w));
  float4 of = { o[0], o[1], o[2], o[3] };
  ((float4*)hp)[i4] = of;
  ushort hi[4], lo[4];
#pragma unroll
  for (int k = 0; k < 4; k++) split2(o[k], hi[k], lo[k]);
  uint2 ph, pl;
  ph.x = (uint)hi[0] | ((uint)hi[1] << 16);
  ph.y = (uint)hi[2] | ((uint)hi[3] << 16);
  pl.x = (uint)lo[0] | ((uint)lo[1] << 16);
  pl.y = (uint)lo[2] | ((uint)lo[3] << 16);
  ((uint2*)hhi)[i4] = ph;
  ((uint2*)hlo)[i4] = pl;
}

// ------------- static weight transposes (Wo, W2) -> bf16 hi/lo [N][K] -------------
__global__ __launch_bounds__(256) void t_wo(const float* __restrict__ Wo,
    ushort* __restrict__ dhi, ushort* __restrict__ dlo)
{
  int i = blockIdx.x * 256 + threadIdx.x;     // L*128*128 = 49152 exact
  int l = i / 16384, r = i % 16384;
  int n = r >> 7, k = r & 127;
  int hh = k >> 4, kd = k & 15;
  float w = Wo[l*16384 + hh*2048 + kd*128 + n];
  split2(w, dhi[i], dlo[i]);
}
__global__ __launch_bounds__(256) void t_w2(const float* __restrict__ W2,
    ushort* __restrict__ dhi, ushort* __restrict__ dlo)
{
  int i = blockIdx.x * 256 + threadIdx.x;     // L*128*512 = 196608 exact
  int l = i / 65536, r = i % 65536;
  int d = r >> 9, f = r & 511;
  float w = W2[l*65536 + f*128 + d];
  split2(w, dhi[i], dlo[i]);
}

// ------------- init BN-fold state to identity -------------
__global__ __launch_bounds__(128) void init_scales(float* __restrict__ sc, float* __restrict__ sh)
{
  int c = threadIdx.x;
  sc[c] = 1.f;
  sh[c] = 0.f;
}

// ------------- fold BN into QKV weights (PARALLEL: block=n-row, thread=k) -------------
__global__ __launch_bounds__(128) void fold_qkv(const float* __restrict__ Wq,
    const float* __restrict__ Wk, const float* __restrict__ Wv,
    const float* __restrict__ sc, const float* __restrict__ sh,
    ushort* __restrict__ whi, ushort* __restrict__ wlo, float* __restrict__ bout)
{
  __shared__ float wsum[2];
  int n = blockIdx.x;                     // 0..383
  int k = threadIdx.x;                    // 0..127
  int which = n >> 7, hh = (n >> 4) & 7, kd = n & 15;
  const float* src = (which == 0) ? Wq : (which == 1) ? Wk : Wv;
  float w = src[hh*2048 + k*16 + kd];
  split2(w * sc[k], whi[n*128 + k], wlo[n*128 + k]);   // coalesced writes over k
  float p = sh[k] * w;
#pragma unroll
  for (int d = 1; d < 64; d <<= 1) p += __shfl_xor(p, d);
  if ((k & 63) == 0) wsum[k >> 6] = p;
  __syncthreads();
  if (k == 0) bout[n] = wsum[0] + wsum[1];
}

// ------------- fold BN into W1 (PARALLEL: block=f-row, thread=k) -------------
__global__ __launch_bounds__(128) void fold_w1(const float* __restrict__ W1,
    const float* __restrict__ b1, const float* __restrict__ sc, const float* __restrict__ sh,
    ushort* __restrict__ whi, ushort* __restrict__ wlo, float* __restrict__ bout)
{
  __shared__ float wsum[2];
  int f = blockIdx.x;                     // 0..511
  int k = threadIdx.x;                    // 0..127
  float w = W1[k*512 + f];
  split2(w * sc[k], whi[f*128 + k], wlo[f*128 + k]);
  float p = sh[k] * w;
#pragma unroll
  for (int d = 1; d < 64; d <<= 1) p += __shfl_xor(p, d);
  if ((k & 63) == 0) wsum[k >> 6] = p;
  __syncthreads();
  if (k == 0) bout[f] = b1[f] + wsum[0] + wsum[1];
}

// ---------------- split-bf16 MFMA GEMM: BK=64 XOR-swizzle body + BN-fold epilogue ----------------
template<int K, bool BIAS, bool RELU, bool RESIDBN, bool OUTF32, bool OUTHL, bool STATS>
__global__ __launch_bounds__(256, 2) void gemm_mfma(
    const ushort* __restrict__ Ahi, const ushort* __restrict__ Alo,
    const ushort* __restrict__ Whi, const ushort* __restrict__ Wlo,
    const float* __restrict__ bias,
    const float* __restrict__ residf, const float* __restrict__ rsc, const float* __restrict__ rsh,
    float* __restrict__ Cf, ushort* __restrict__ Chi, ushort* __restrict__ Clo,
    float* __restrict__ psum, float* __restrict__ psq, int Ntot)
{
  __shared__ ushort AhiS[128*64];
  __shared__ ushort AloS[128*64];
  __shared__ ushort BhiS[128*64];
  __shared__ ushort BloS[128*64];
  const int t    = threadIdx.x;
  const int bm   = blockIdx.y * 128;
  const int bn   = blockIdx.x * 128;
  const int lane = t & 63;
  const int w    = t >> 6, wm = w >> 1, wn = w & 1;
  const int quad = lane >> 4, l15 = lane & 15;

  f32x4 acc[4][4];
#pragma unroll
  for (int i = 0; i < 4; i++)
#pragma unroll
    for (int j = 0; j < 4; j++) acc[i][j] = (f32x4){0.f, 0.f, 0.f, 0.f};

  const ushort* AhiB = Ahi + (size_t)bm * K;
  const ushort* AloB = Alo + (size_t)bm * K;
  const ushort* BhiB = Whi + (size_t)bn * K;
  const ushort* BloB = Wlo + (size_t)bn * K;

  for (int k0 = 0; k0 < K; k0 += 64) {
#pragma unroll
    for (int i = 0; i < 4; i++) {
      int idx = i * 256 + t;
      int row = idx >> 3, c = idx & 7;
      int k8  = c ^ (row & 7);
      size_t off = (size_t)row * K + k0 + k8 * 8;
      ((uint4*)AhiS)[idx] = *(const uint4*)(AhiB + off);
      ((uint4*)AloS)[idx] = *(const uint4*)(AloB + off);
      ((uint4*)BhiS)[idx] = *(const uint4*)(BhiB + off);
      ((uint4*)BloS)[idx] = *(const uint4*)(BloB + off);
    }
    __syncthreads();
#pragma unroll
    for (int ks = 0; ks < 2; ks++) {
      bf16x8 ah[4], al[4], bh[4], bl[4];
#pragma unroll
      for (int i = 0; i < 4; i++) {
        int row = wm * 64 + i * 16 + l15;
        int k8  = ks * 4 + quad;
        int ci  = k8 ^ (row & 7);
        ah[i] = ((const bf16x8*)AhiS)[row * 8 + ci];
        al[i] = ((const bf16x8*)AloS)[row * 8 + ci];
        int nrow = wn * 64 + i * 16 + l15;
        int cj   = k8 ^ (nrow & 7);
        bh[i] = ((const bf16x8*)BhiS)[nrow * 8 + cj];
        bl[i] = ((const bf16x8*)BloS)[nrow * 8 + cj];
      }
#pragma unroll
      for (int i = 0; i < 4; i++)
#pragma unroll
        for (int j = 0; j < 4; j++) {
          acc[i][j] = __builtin_amdgcn_mfma_f32_16x16x32_bf16(al[i], bh[j], acc[i][j], 0, 0, 0);
          acc[i][j] = __builtin_amdgcn_mfma_f32_16x16x32_bf16(ah[i], bl[j], acc[i][j], 0, 0, 0);
          acc[i][j] = __builtin_amdgcn_mfma_f32_16x16x32_bf16(ah[i], bh[j], acc[i][j], 0, 0, 0);
        }
    }
    __syncthreads();
  }

  float bv[4], scv[4], shv[4];
#pragma unroll
  for (int j = 0; j < 4; j++) {
    int col = bn + wn*64 + j*16 + l15;
    if (BIAS)    bv[j]  = bias[col];
    if (RESIDBN) { scv[j] = rsc[col]; shv[j] = rsh[col]; }
  }
  float sj[4] = {0.f,0.f,0.f,0.f}, qj[4] = {0.f,0.f,0.f,0.f};
#pragma unroll
  for (int i = 0; i < 4; i++) {
#pragma unroll
    for (int r = 0; r < 4; r++) {
      int row = bm + wm*64 + i*16 + quad*4 + r;
#pragma unroll
      for (int j = 0; j < 4; j++) {
        int col = bn + wn*64 + j*16 + l15;
        float v = acc[i][j][r];
        if (BIAS)    v += bv[j];
        if (RELU)    v = fmaxf(v, 0.f);
        if (RESIDBN) v += fmaf(residf[(size_t)row * Ntot + col], scv[j], shv[j]);
        if (OUTF32)  Cf[(size_t)row * Ntot + col] = v;
        if (OUTHL) {
          ushort hi, lo;
          split2(v, hi, lo);
          Chi[(size_t)row * Ntot + col] = hi;
          Clo[(size_t)row * Ntot + col] = lo;
        }
        if (STATS) { sj[j] += v; qj[j] = fmaf(v, v, qj[j]); }
      }
    }
  }
  if (STATS) {
#pragma unroll
    for (int j = 0; j < 4; j++) {
      sj[j] += __shfl_xor(sj[j], 16); sj[j] += __shfl_xor(sj[j], 32);
      qj[j] += __shfl_xor(qj[j], 16); qj[j] += __shfl_xor(qj[j], 32);
    }
    float* ssum = (float*)AhiS;     // safe: k-loop ended with barrier
    float* ssq  = ssum + 128;
    if (t < 128) { ssum[t] = 0.f; ssq[t] = 0.f; }
    __syncthreads();
    if (quad == 0) {
#pragma unroll
      for (int j = 0; j < 4; j++) {
        int col = wn*64 + j*16 + l15;
        atomicAdd(&ssum[col], sj[j]);
        atomicAdd(&ssq[col],  qj[j]);
      }
    }
    __syncthreads();
    if (t < 128) {
      psum[blockIdx.y * 128 + t] = ssum[t];
      psq [blockIdx.y * 128 + t] = ssq[t];
    }
  }
}

// ---------------- fused attention: bf16 hi/lo qkv input, fp16-dot2 scores ----------------
// Q/K/V arrive as bf16 hi/lo [row][384]. Staging reconstructs hi+lo:
// K -> fp16 LDS (with later 0.25 fold on q), V -> fp32 LDS. Scores via v_dot2_f32_f16.
__global__ __launch_bounds__(256) void attn_kernel(
    const ushort* __restrict__ Qhi, const ushort* __restrict__ Qlo,
    ushort* __restrict__ Ohi, ushort* __restrict__ Olo)
{
  __shared__ __align__(16) h16x2 Ksh[N_][8];           // 16 fp16 per key
  __shared__ __align__(16) float Vs[N_][KD_];
  const int b  = blockIdx.x >> 3;
  const int hh = blockIdx.x & 7;
  const int t  = threadIdx.x;
  const size_t rowbase = (size_t)(b * N_) * 384;
  for (int i = t; i < N_ * 4; i += 256) {
    int n = i >> 2, part = i & 3;                       // 8 elements per part
    if (part < 2) {
      // K dims part*8 .. part*8+7 -> fp16
      const ushort* ph = Qhi + rowbase + n*384 + 128 + hh*16 + part*8;
      const ushort* pl = Qlo + rowbase + n*384 + 128 + hh*16 + part*8;
      uint4 uh = *(const uint4*)ph;
      uint4 ul = *(const uint4*)pl;
      const ushort* hs = (const ushort*)&uh;
      const ushort* ls = (const ushort*)&ul;
      h16x2 out[4];
#pragma unroll
      for (int e = 0; e < 4; e++) {
        float f0 = bf2f(hs[e*2])   + bf2f(ls[e*2]);
        float f1 = bf2f(hs[e*2+1]) + bf2f(ls[e*2+1]);
        h16x2 v = { (_Float16)f0, (_Float16)f1 };
        out[e] = v;
      }
      *(uint4*)&Ksh[n][part*4] = *(uint4*)out;
    } else {
      // V dims (part-2)*8 .. +7 -> fp32
      int g = (part - 2) * 8;
      const ushort* ph = Qhi + rowbase + n*384 + 256 + hh*16 + g;
      const ushort* pl = Qlo + rowbase + n*384 + 256 + hh*16 + g;
      uint4 uh = *(const uint4*)ph;
      uint4 ul = *(const uint4*)pl;
      const ushort* hs = (const ushort*)&uh;
      const ushort* ls = (const ushort*)&ul;
      float f[8];
#pragma unroll
      for (int e = 0; e < 8; e++) f[e] = bf2f(hs[e]) + bf2f(ls[e]);
      float4 v0 = { f[0], f[1], f[2], f[3] };
      float4 v1 = { f[4], f[5], f[6], f[7] };
      ((float4*)&Vs[n][0])[(g >> 2)]     = v0;
      ((float4*)&Vs[n][0])[(g >> 2) + 1] = v1;
    }
  }
  __syncthreads();
  if (t < N_) {
    h16x2 qh[8];
#pragma unroll
    for (int g = 0; g < 2; g++) {
      uint4 uh = *(const uint4*)(Qhi + rowbase + t*384 + hh*16 + g*8);
      uint4 ul = *(const uint4*)(Qlo + rowbase + t*384 + hh*16 + g*8);
      const ushort* hs = (const ushort*)&uh;
      const ushort* ls = (const ushort*)&ul;
#pragma unroll
      for (int e = 0; e < 4; e++) {
        float f0 = (bf2f(hs[e*2])   + bf2f(ls[e*2]))   * 0.25f;
        float f1 = (bf2f(hs[e*2+1]) + bf2f(ls[e*2+1])) * 0.25f;
        h16x2 v = { (_Float16)f0, (_Float16)f1 };
        qh[g*4 + e] = v;
      }
    }
    float m = -1e30f, l = 0.f;
    float o[KD_] = {0.f};
    for (int c0 = 0; c0 < N_; c0 += 40) {
      float s[40];
      float cmax = -1e30f;
#pragma unroll
      for (int j = 0; j < 40; j++) {
        const h16x2* kr = &Ksh[c0 + j][0];
        float a = 0.f;
#pragma unroll
        for (int e = 0; e < 8; e++)
          a = __builtin_amdgcn_fdot2(qh[e], kr[e], a, false);
        s[j] = a;
        cmax = fmaxf(cmax, a);
      }
      float mn   = fmaxf(m, cmax);
      float corr = __expf(m - mn);
      l *= corr;
#pragma unroll
      for (int kk = 0; kk < KD_; kk++) o[kk] *= corr;
#pragma unroll
      for (int j = 0; j < 40; j++) {
        float p = __expf(s[j] - mn);
        l += p;
        const float4* vr = (const float4*)&Vs[c0 + j][0];
        float4 v0 = vr[0], v1 = vr[1], v2 = vr[2], v3 = vr[3];
        o[0]  = fmaf(p, v0.x, o[0]);  o[1]  = fmaf(p, v0.y, o[1]);
        o[2]  = fmaf(p, v0.z, o[2]);  o[3]  = fmaf(p, v0.w, o[3]);
        o[4]  = fmaf(p, v1.x, o[4]);  o[5]  = fmaf(p, v1.y, o[5]);
        o[6]  = fmaf(p, v1.z, o[6]);  o[7]  = fmaf(p, v1.w, o[7]);
        o[8]  = fmaf(p, v2.x, o[8]);  o[9]  = fmaf(p, v2.y, o[9]);
        o[10] = fmaf(p, v2.z, o[10]); o[11] = fmaf(p, v2.w, o[11]);
        o[12] = fmaf(p, v3.x, o[12]); o[13] = fmaf(p, v3.y, o[13]);
        o[14] = fmaf(p, v3.z, o[14]); o[15] = fmaf(p, v3.w, o[15]);
      }
      m = mn;
    }
    float inv = 1.f / l;
    ushort hi[16], lo[16];
#pragma unroll
    for (int kk = 0; kk < KD_; kk++) split2(o[kk] * inv, hi[kk], lo[kk]);
    size_t obase = ((size_t)(b * N_ + t)) * 128 + hh * 16;
    uint4 ph0, ph1, pl0, pl1;
    ph0.x = (uint)hi[0]  | ((uint)hi[1]  << 16); ph0.y = (uint)hi[2]  | ((uint)hi[3]  << 16);
    ph0.z = (uint)hi[4]  | ((uint)hi[5]  << 16); ph0.w = (uint)hi[6]  | ((uint)hi[7]  << 16);
    ph1.x = (uint)hi[8]  | ((uint)hi[9]  << 16); ph1.y = (uint)hi[10] | ((uint)hi[11] << 16);
    ph1.z = (uint)hi[12] | ((uint)hi[13] << 16); ph1.w = (uint)hi[14] | ((uint)hi[15] << 16);
    pl0.x = (uint)lo[0]  | ((uint)lo[1]  << 16); pl0.y = (uint)lo[2]  | ((uint)lo[3]  << 16);
    pl0.z = (uint)lo[4]  | ((uint)lo[5]  << 16); pl0.w = (uint)lo[6]  | ((uint)lo[7]  << 16);
    pl1.x = (uint)lo[8]  | ((uint)lo[9]  << 16); pl1.y = (uint)lo[10] | ((uint)lo[11] << 16);
    pl1.z = (uint)lo[12] | ((uint)lo[13] << 16); pl1.w = (uint)lo[14] | ((uint)lo[15] << 16);
    ((uint4*)(Ohi + obase))[0] = ph0;
    ((uint4*)(Ohi + obase))[1] = ph1;
    ((uint4*)(Olo + obase))[0] = pl0;
    ((uint4*)(Olo + obase))[1] = pl1;
  }
}

// ---------------- BN finalize: PARALLEL (block=channel, wave reduce 400 partials) ----------------
__global__ __launch_bounds__(64) void bn_finalize(const float* __restrict__ psum,
    const float* __restrict__ psq, const float* __restrict__ g,
    const float* __restrict__ bta, float* __restrict__ scale, float* __restrict__ shift)
{
  int c = blockIdx.x;        // 0..127
  int i = threadIdx.x;       // 0..63
  float s = 0.f, q = 0.f;
  for (int r = i; r < 400; r += 64) { s += psum[r*128 + c]; q += psq[r*128 + c]; }
#pragma unroll
  for (int d = 32; d > 0; d >>= 1) { s += __shfl_down(s, d); q += __shfl_down(q, d); }
  if (i == 0) {
    const float invM = 1.f / 51200.f;
    float m  = s * invM;
    float v  = fmaf(q, invM, -m * m);
    float r  = rsqrtf(v + 1e-5f);
    float sc = r * g[c];
    scale[c] = sc;
    shift[c] = fmaf(-m, sc, bta[c]);
  }
}

// ---------------- final BN apply (in place, fp32) ----------------
__global__ __launch_bounds__(256) void bn_apply_final(float* __restrict__ hp,
    const float* __restrict__ scale, const float* __restrict__ shift)
{
  int i4 = blockIdx.x * 256 + threadIdx.x;   // ROWS*32 exact
  int c4 = i4 & 31;
  float4 v  = ((float4*)hp)[i4];
  float4 sc = ((const float4*)scale)[c4];
  float4 sh = ((const float4*)shift)[c4];
  v.x = fmaf(v.x, sc.x, sh.x);
  v.y = fmaf(v.y, sc.y, sh.y);
  v.z = fmaf(v.z, sc.z, sh.z);
  v.w = fmaf(v.w, sc.w, sh.w);
  ((float4*)hp)[i4] = v;
}

// ---------------- final mean over N ----------------
__global__ __launch_bounds__(128) void mean_kernel(const float* __restrict__ h,
                                                   float* __restrict__ out)
{
  int b = blockIdx.x, d = threadIdx.x;
  const float* p = h + (size_t)b * N_ * D_ + d;
  float s = 0.f;
  for (int n = 0; n < N_; n++) s += p[n * D_];
  out[b * D_ + d] = s * (1.f / N_);
}

extern "C" void kernel_launch(void* const* d_in, const int* in_sizes, int n_in,
                              void* d_out, int out_size, void* d_ws, size_t ws_size,
                              hipStream_t stream)
{
  const float* x    = (const float*)d_in[0];
  const float* Wemb = (const float*)d_in[1];
  const float* bemb = (const float*)d_in[2];
  const float* Wq   = (const float*)d_in[3];
  const float* Wk   = (const float*)d_in[4];
  const float* Wv   = (const float*)d_in[5];
  const float* Wo   = (const float*)d_in[6];
  const float* bn1g = (const float*)d_in[7];
  const float* bn1b = (const float*)d_in[8];
  const float* W1   = (const float*)d_in[9];
  const float* b1   = (const float*)d_in[10];
  const float* W2   = (const float*)d_in[11];
  const float* b2   = (const float*)d_in[12];
  const float* bn2g = (const float*)d_in[13];
  const float* bn2b = (const float*)d_in[14];
  float* out = (float*)d_out;

  // rolling pre-BN residual state hp lives in d_out[0:BND]
  float* hp = out;

  char* wsb = (char*)d_ws;
  ushort* h_hi  = (ushort*)wsb;                     // 13,107,200 B
  ushort* h_lo  = (ushort*)(wsb + 13107200);        // 13,107,200 B
  char*   phase = wsb + 26214400;                   // 104,857,600 B union
  ushort* qkv_hi = (ushort*)phase;                  //   attn: 39,321,600 B
  ushort* qkv_lo = (ushort*)(phase + 39321600);     //   attn: 39,321,600 B
  ushort* hd_hi  = (ushort*)(phase + 78643200);     //   attn: 13,107,200 B
  ushort* hd_lo  = (ushort*)(phase + 91750400);     //   attn: 13,107,200 B
  ushort* hid_hi = (ushort*)phase;                  //   ffn: 52,428,800 B
  ushort* hid_lo = (ushort*)(phase + 52428800);     //   ffn: 52,428,800 B
  char*   wp    = wsb + 131072000;
  ushort* woT_hi  = (ushort*)wp;                    // 98,304 B
  ushort* woT_lo  = (ushort*)(wp + 98304);          // 98,304 B
  ushort* w2T_hi  = (ushort*)(wp + 196608);         // 393,216 B
  ushort* w2T_lo  = (ushort*)(wp + 589824);         // 393,216 B
  ushort* fqkv_hi = (ushort*)(wp + 983040);         // 98,304 B
  ushort* fqkv_lo = (ushort*)(wp + 1081344);        // 98,304 B
  ushort* fw1_hi  = (ushort*)(wp + 1179648);        // 131,072 B
  ushort* fw1_lo  = (ushort*)(wp + 1310720);        // 131,072 B
  float*  fqkv_b  = (float*)(wp + 1441792);         // 1,536 B
  float*  fw1_b   = (float*)(wp + 1443328);         // 2,048 B
  float*  psum    = (float*)(wp + 1445376);         // 204,800 B
  float*  psq     = (float*)(wp + 1650176);         // 204,800 B
  float*  sc_a    = (float*)(wp + 1854976);
  float*  sh_a    = (float*)(wp + 1855488);
  float*  sc_b    = (float*)(wp + 1856000);
  float*  sh_b    = (float*)(wp + 1856512);

  embed_kernel<<<6400, 256, 0, stream>>>(x, Wemb, bemb, hp, h_hi, h_lo);
  t_wo<<<192, 256, 0, stream>>>(Wo, woT_hi, woT_lo);
  t_w2<<<768, 256, 0, stream>>>(W2, w2T_hi, w2T_lo);
  init_scales<<<1, 128, 0, stream>>>(sc_b, sh_b);

  for (int l = 0; l < L_; l++) {
    // fold BN(prev layer / identity) into QKV weights (parallel, coalesced)
    fold_qkv<<<384, 128, 0, stream>>>(Wq + l*16384, Wk + l*16384, Wv + l*16384,
                                      sc_b, sh_b, fqkv_hi, fqkv_lo, fqkv_b);
    // QKV projection -> qkv bf16 hi/lo [rows][384]
    gemm_mfma<128, true, false, false, false, true, false><<<dim3(3, 400), 256, 0, stream>>>(
        h_hi, h_lo, fqkv_hi, fqkv_lo, fqkv_b, nullptr, nullptr, nullptr,
        nullptr, qkv_hi, qkv_lo, nullptr, nullptr, 384);
    // attention -> heads hi/lo
    attn_kernel<<<B_ * H_, 256, 0, stream>>>(qkv_hi, qkv_lo, hd_hi, hd_lo);
    // out-proj + BN-folded residual -> hp (h1_pre) fp32 + hi/lo + BN1 stats
    gemm_mfma<128, false, false, true, true, true, true><<<dim3(1, 400), 256, 0, stream>>>(
        hd_hi, hd_lo, woT_hi + l*16384, woT_lo + l*16384, nullptr, hp, sc_b, sh_b,
        hp, h_hi, h_lo, psum, psq, 128);
    bn_finalize<<<128, 64, 0, stream>>>(psum, psq, bn1g + l*128, bn1b + l*128, sc_a, sh_a);
    // fold BN1 into W1 (parallel, coalesced)
    fold_w1<<<512, 128, 0, stream>>>(W1 + l*65536, b1 + l*512, sc_a, sh_a, fw1_hi, fw1_lo, fw1_b);
    // FFN1 + folded bias + relu -> hidden hi/lo
    gemm_mfma<128, true, true, false, false, true, false><<<dim3(4, 400), 256, 0, stream>>>(
        h_hi, h_lo, fw1_hi, fw1_lo, fw1_b, nullptr, nullptr, nullptr,
        nullptr, hid_hi, hid_lo, nullptr, nullptr, 512);
    // FFN2 + bias + BN1-folded residual -> hp (h2_pre) fp32 + hi/lo + BN2 stats
    gemm_mfma<512, true, false, true, true, true, true><<<dim3(1, 400), 256, 0, stream>>>(
        hid_hi, hid_lo, w2T_hi + l*65536, w2T_lo + l*65536, b2 + l*128, hp, sc_a, sh_a,
        hp, h_hi, h_lo, psum, psq, 128);
    bn_finalize<<<128, 64, 0, stream>>>(psum, psq, bn2g + l*128, bn2b + l*128, sc_b, sh_b);
  }

  bn_apply_final<<<6400, 256, 0, stream>>>(hp, sc_b, sh_b);
  mean_kernel<<<B_, 128, 0, stream>>>(hp, out + BND);
}

// Round 13
// 808.967 us; speedup vs baseline: 1.2308x; 1.0794x over previous
//
#include <hip/hip_runtime.h>
#include <math.h>

#define B_ 256
#define N_ 200
#define D_ 128
#define H_ 8
#define KD_ 16
#define L_ 3
#define FF_ 512
#define ROWS (B_*N_)          // 51200
#define BND (ROWS*D_)         // 6,553,600

typedef __bf16 bf16x8 __attribute__((ext_vector_type(8)));
typedef float f32x4 __attribute__((ext_vector_type(4)));
typedef _Float16 h16x2 __attribute__((ext_vector_type(2)));

__device__ __forceinline__ ushort f2bf(float f) {
  union { float f; unsigned u; } v; v.f = f;
  unsigned r = v.u + 0x7fffu + ((v.u >> 16) & 1u);
  return (ushort)(r >> 16);
}
__device__ __forceinline__ float bf2f(ushort h) {
  union { unsigned u; float f; } v; v.u = ((unsigned)h) << 16; return v.f;
}
__device__ __forceinline__ void split2(float f, ushort& hi, ushort& lo) {
  hi = f2bf(f);
  lo = f2bf(f - bf2f(hi));
}

// ---------------- embed: h = x @ Wemb + bemb -> hp fp32 + hi/lo bf16 ----------------
__global__ __launch_bounds__(256) void embed_kernel(const float* __restrict__ x,
    const float* __restrict__ Wemb, const float* __restrict__ bemb,
    float* __restrict__ hp, ushort* __restrict__ hhi, ushort* __restrict__ hlo)
{
  int i4 = blockIdx.x * 256 + threadIdx.x;   // ROWS*32 float4s
  int r  = i4 >> 5, c4 = i4 & 31;
  float x0 = x[2*r], x1 = x[2*r + 1];
  const float4 w0 = ((const float4*)Wemb)[c4];
  const float4 w1 = ((const float4*)Wemb)[32 + c4];
  const float4 bb = ((const float4*)bemb)[c4];
  float o[4];
  o[0] = fmaf(x0, w0.x, fmaf(x1, w1.x, bb.x));
  o[1] = fmaf(x0, w0.y, fmaf(x1, w1.y, bb.y));
  o[2] = fmaf(x0, w0.z, fmaf(x1, w1.z, bb.z));
  o[3] = fmaf(x0, w0.w, fmaf(x1, w1.w, bb.w));
  float4 of = { o[0], o[1], o[2], o[3] };
  ((float4*)hp)[i4] = of;
  ushort hi[4], lo[4];
#pragma unroll
  for (int k = 0; k < 4; k++) split2(o[k], hi[k], lo[k]);
  uint2 ph, pl;
  ph.x = (uint)hi[0] | ((uint)hi[1] << 16);
  ph.y = (uint)hi[2] | ((uint)hi[3] << 16);
  pl.x = (uint)lo[0] | ((uint)lo[1] << 16);
  pl.y = (uint)lo[2] | ((uint)lo[3] << 16);
  ((uint2*)hhi)[i4] = ph;
  ((uint2*)hlo)[i4] = pl;
}

// ------------- static weight transposes (Wo, W2) -> bf16 hi/lo [N][K] -------------
__global__ __launch_bounds__(256) void t_wo(const float* __restrict__ Wo,
    ushort* __restrict__ dhi, ushort* __restrict__ dlo)
{
  int i = blockIdx.x * 256 + threadIdx.x;     // L*128*128 = 49152 exact
  int l = i / 16384, r = i % 16384;
  int n = r >> 7, k = r & 127;
  int hh = k >> 4, kd = k & 15;
  float w = Wo[l*16384 + hh*2048 + kd*128 + n];
  split2(w, dhi[i], dlo[i]);
}
__global__ __launch_bounds__(256) void t_w2(const float* __restrict__ W2,
    ushort* __restrict__ dhi, ushort* __restrict__ dlo)
{
  int i = blockIdx.x * 256 + threadIdx.x;     // L*128*512 = 196608 exact
  int l = i / 65536, r = i % 65536;
  int d = r >> 9, f = r & 511;
  float w = W2[l*65536 + f*128 + d];
  split2(w, dhi[i], dlo[i]);
}

// ------------- init BN-fold state to identity -------------
__global__ __launch_bounds__(128) void init_scales(float* __restrict__ sc, float* __restrict__ sh)
{
  int c = threadIdx.x;
  sc[c] = 1.f;
  sh[c] = 0.f;
}

// ------------- fold BN into QKV weights (PARALLEL: block=n-row, thread=k) -------------
__global__ __launch_bounds__(128) void fold_qkv(const float* __restrict__ Wq,
    const float* __restrict__ Wk, const float* __restrict__ Wv,
    const float* __restrict__ sc, const float* __restrict__ sh,
    ushort* __restrict__ whi, ushort* __restrict__ wlo, float* __restrict__ bout)
{
  __shared__ float wsum[2];
  int n = blockIdx.x;                     // 0..383
  int k = threadIdx.x;                    // 0..127
  int which = n >> 7, hh = (n >> 4) & 7, kd = n & 15;
  const float* src = (which == 0) ? Wq : (which == 1) ? Wk : Wv;
  float w = src[hh*2048 + k*16 + kd];
  split2(w * sc[k], whi[n*128 + k], wlo[n*128 + k]);   // coalesced writes over k
  float p = sh[k] * w;
#pragma unroll
  for (int d = 1; d < 64; d <<= 1) p += __shfl_xor(p, d);
  if ((k & 63) == 0) wsum[k >> 6] = p;
  __syncthreads();
  if (k == 0) bout[n] = wsum[0] + wsum[1];
}

// ------------- fold BN into W1 (PARALLEL: block=f-row, thread=k) -------------
__global__ __launch_bounds__(128) void fold_w1(const float* __restrict__ W1,
    const float* __restrict__ b1, const float* __restrict__ sc, const float* __restrict__ sh,
    ushort* __restrict__ whi, ushort* __restrict__ wlo, float* __restrict__ bout)
{
  __shared__ float wsum[2];
  int f = blockIdx.x;                     // 0..511
  int k = threadIdx.x;                    // 0..127
  float w = W1[k*512 + f];
  split2(w * sc[k], whi[f*128 + k], wlo[f*128 + k]);
  float p = sh[k] * w;
#pragma unroll
  for (int d = 1; d < 64; d <<= 1) p += __shfl_xor(p, d);
  if ((k & 63) == 0) wsum[k >> 6] = p;
  __syncthreads();
  if (k == 0) bout[f] = b1[f] + wsum[0] + wsum[1];
}

// ---------------- split-bf16 MFMA GEMM: BK=64 XOR-swizzle body + BN-fold epilogue ----------------
template<int K, bool BIAS, bool RELU, bool RESIDBN, bool OUTF32, bool OUTHL, bool STATS>
__global__ __launch_bounds__(256, 2) void gemm_mfma(
    const ushort* __restrict__ Ahi, const ushort* __restrict__ Alo,
    const ushort* __restrict__ Whi, const ushort* __restrict__ Wlo,
    const float* __restrict__ bias,
    const float* __restrict__ residf, const float* __restrict__ rsc, const float* __restrict__ rsh,
    float* __restrict__ Cf, ushort* __restrict__ Chi, ushort* __restrict__ Clo,
    float* __restrict__ psum, float* __restrict__ psq, int Ntot)
{
  __shared__ ushort AhiS[128*64];
  __shared__ ushort AloS[128*64];
  __shared__ ushort BhiS[128*64];
  __shared__ ushort BloS[128*64];
  const int t    = threadIdx.x;
  const int bm   = blockIdx.y * 128;
  const int bn   = blockIdx.x * 128;
  const int lane = t & 63;
  const int w    = t >> 6, wm = w >> 1, wn = w & 1;
  const int quad = lane >> 4, l15 = lane & 15;

  f32x4 acc[4][4];
#pragma unroll
  for (int i = 0; i < 4; i++)
#pragma unroll
    for (int j = 0; j < 4; j++) acc[i][j] = (f32x4){0.f, 0.f, 0.f, 0.f};

  const ushort* AhiB = Ahi + (size_t)bm * K;
  const ushort* AloB = Alo + (size_t)bm * K;
  const ushort* BhiB = Whi + (size_t)bn * K;
  const ushort* BloB = Wlo + (size_t)bn * K;

  for (int k0 = 0; k0 < K; k0 += 64) {
#pragma unroll
    for (int i = 0; i < 4; i++) {
      int idx = i * 256 + t;
      int row = idx >> 3, c = idx & 7;
      int k8  = c ^ (row & 7);
      size_t off = (size_t)row * K + k0 + k8 * 8;
      ((uint4*)AhiS)[idx] = *(const uint4*)(AhiB + off);
      ((uint4*)AloS)[idx] = *(const uint4*)(AloB + off);
      ((uint4*)BhiS)[idx] = *(const uint4*)(BhiB + off);
      ((uint4*)BloS)[idx] = *(const uint4*)(BloB + off);
    }
    __syncthreads();
#pragma unroll
    for (int ks = 0; ks < 2; ks++) {
      bf16x8 ah[4], al[4], bh[4], bl[4];
#pragma unroll
      for (int i = 0; i < 4; i++) {
        int row = wm * 64 + i * 16 + l15;
        int k8  = ks * 4 + quad;
        int ci  = k8 ^ (row & 7);
        ah[i] = ((const bf16x8*)AhiS)[row * 8 + ci];
        al[i] = ((const bf16x8*)AloS)[row * 8 + ci];
        int nrow = wn * 64 + i * 16 + l15;
        int cj   = k8 ^ (nrow & 7);
        bh[i] = ((const bf16x8*)BhiS)[nrow * 8 + cj];
        bl[i] = ((const bf16x8*)BloS)[nrow * 8 + cj];
      }
#pragma unroll
      for (int i = 0; i < 4; i++)
#pragma unroll
        for (int j = 0; j < 4; j++) {
          acc[i][j] = __builtin_amdgcn_mfma_f32_16x16x32_bf16(al[i], bh[j], acc[i][j], 0, 0, 0);
          acc[i][j] = __builtin_amdgcn_mfma_f32_16x16x32_bf16(ah[i], bl[j], acc[i][j], 0, 0, 0);
          acc[i][j] = __builtin_amdgcn_mfma_f32_16x16x32_bf16(ah[i], bh[j], acc[i][j], 0, 0, 0);
        }
    }
    __syncthreads();
  }

  float bv[4], scv[4], shv[4];
#pragma unroll
  for (int j = 0; j < 4; j++) {
    int col = bn + wn*64 + j*16 + l15;
    if (BIAS)    bv[j]  = bias[col];
    if (RESIDBN) { scv[j] = rsc[col]; shv[j] = rsh[col]; }
  }
  float sj[4] = {0.f,0.f,0.f,0.f}, qj[4] = {0.f,0.f,0.f,0.f};
#pragma unroll
  for (int i = 0; i < 4; i++) {
#pragma unroll
    for (int r = 0; r < 4; r++) {
      int row = bm + wm*64 + i*16 + quad*4 + r;
#pragma unroll
      for (int j = 0; j < 4; j++) {
        int col = bn + wn*64 + j*16 + l15;
        float v = acc[i][j][r];
        if (BIAS)    v += bv[j];
        if (RELU)    v = fmaxf(v, 0.f);
        if (RESIDBN) v += fmaf(residf[(size_t)row * Ntot + col], scv[j], shv[j]);
        if (OUTF32)  Cf[(size_t)row * Ntot + col] = v;
        if (OUTHL) {
          ushort hi, lo;
          split2(v, hi, lo);
          Chi[(size_t)row * Ntot + col] = hi;
          Clo[(size_t)row * Ntot + col] = lo;
        }
        if (STATS) { sj[j] += v; qj[j] = fmaf(v, v, qj[j]); }
      }
    }
  }
  if (STATS) {
#pragma unroll
    for (int j = 0; j < 4; j++) {
      sj[j] += __shfl_xor(sj[j], 16); sj[j] += __shfl_xor(sj[j], 32);
      qj[j] += __shfl_xor(qj[j], 16); qj[j] += __shfl_xor(qj[j], 32);
    }
    float* ssum = (float*)AhiS;     // safe: k-loop ended with barrier
    float* ssq  = ssum + 128;
    if (t < 128) { ssum[t] = 0.f; ssq[t] = 0.f; }
    __syncthreads();
    if (quad == 0) {
#pragma unroll
      for (int j = 0; j < 4; j++) {
        int col = wn*64 + j*16 + l15;
        atomicAdd(&ssum[col], sj[j]);
        atomicAdd(&ssq[col],  qj[j]);
      }
    }
    __syncthreads();
    if (t < 128) {
      psum[blockIdx.y * 128 + t] = ssum[t];
      psq [blockIdx.y * 128 + t] = ssq[t];
    }
  }
}

// ---------------- fused attention: fp32 qkv input, fp16-dot2 scores (R11 proven) ----------------
__global__ __launch_bounds__(256) void attn_kernel(const float* __restrict__ qkv,
    ushort* __restrict__ Ohi, ushort* __restrict__ Olo)
{
  __shared__ __align__(16) h16x2 Ksh[N_][8];           // 16 fp16 per key
  __shared__ __align__(16) float Vs[N_][KD_];
  const int b  = blockIdx.x >> 3;
  const int hh = blockIdx.x & 7;
  const int t  = threadIdx.x;
  const float* basep = qkv + (size_t)b * N_ * 384;
  for (int i = t; i < N_ * 8; i += 256) {
    int n = i >> 3, q4 = i & 7;
    if (q4 < 4) {
      float4 v = *(const float4*)(basep + n*384 + 128 + hh*16 + q4*4);
      h16x2 a = { (_Float16)v.x, (_Float16)v.y };
      h16x2 c = { (_Float16)v.z, (_Float16)v.w };
      Ksh[n][q4*2]     = a;
      Ksh[n][q4*2 + 1] = c;
    } else {
      ((float4*)&Vs[n][0])[q4 - 4] = *(const float4*)(basep + n*384 + 256 + hh*16 + (q4-4)*4);
    }
  }
  __syncthreads();
  if (t < N_) {
    h16x2 qh[8];
#pragma unroll
    for (int j4 = 0; j4 < 4; j4++) {
      float4 v4 = *(const float4*)(basep + t*384 + hh*16 + j4*4);
      h16x2 a = { (_Float16)(v4.x * 0.25f), (_Float16)(v4.y * 0.25f) };
      h16x2 c = { (_Float16)(v4.z * 0.25f), (_Float16)(v4.w * 0.25f) };
      qh[j4*2]     = a;
      qh[j4*2 + 1] = c;
    }
    float m = -1e30f, l = 0.f;
    float o[KD_] = {0.f};
    for (int c0 = 0; c0 < N_; c0 += 40) {
      float s[40];
      float cmax = -1e30f;
#pragma unroll
      for (int j = 0; j < 40; j++) {
        const h16x2* kr = &Ksh[c0 + j][0];
        float a = 0.f;
#pragma unroll
        for (int e = 0; e < 8; e++)
          a = __builtin_amdgcn_fdot2(qh[e], kr[e], a, false);
        s[j] = a;
        cmax = fmaxf(cmax, a);
      }
      float mn   = fmaxf(m, cmax);
      float corr = __expf(m - mn);
      l *= corr;
#pragma unroll
      for (int kk = 0; kk < KD_; kk++) o[kk] *= corr;
#pragma unroll
      for (int j = 0; j < 40; j++) {
        float p = __expf(s[j] - mn);
        l += p;
        const float4* vr = (const float4*)&Vs[c0 + j][0];
        float4 v0 = vr[0], v1 = vr[1], v2 = vr[2], v3 = vr[3];
        o[0]  = fmaf(p, v0.x, o[0]);  o[1]  = fmaf(p, v0.y, o[1]);
        o[2]  = fmaf(p, v0.z, o[2]);  o[3]  = fmaf(p, v0.w, o[3]);
        o[4]  = fmaf(p, v1.x, o[4]);  o[5]  = fmaf(p, v1.y, o[5]);
        o[6]  = fmaf(p, v1.z, o[6]);  o[7]  = fmaf(p, v1.w, o[7]);
        o[8]  = fmaf(p, v2.x, o[8]);  o[9]  = fmaf(p, v2.y, o[9]);
        o[10] = fmaf(p, v2.z, o[10]); o[11] = fmaf(p, v2.w, o[11]);
        o[12] = fmaf(p, v3.x, o[12]); o[13] = fmaf(p, v3.y, o[13]);
        o[14] = fmaf(p, v3.z, o[14]); o[15] = fmaf(p, v3.w, o[15]);
      }
      m = mn;
    }
    float inv = 1.f / l;
    ushort hi[16], lo[16];
#pragma unroll
    for (int kk = 0; kk < KD_; kk++) split2(o[kk] * inv, hi[kk], lo[kk]);
    size_t obase = ((size_t)(b * N_ + t)) * 128 + hh * 16;
    uint4 ph0, ph1, pl0, pl1;
    ph0.x = (uint)hi[0]  | ((uint)hi[1]  << 16); ph0.y = (uint)hi[2]  | ((uint)hi[3]  << 16);
    ph0.z = (uint)hi[4]  | ((uint)hi[5]  << 16); ph0.w = (uint)hi[6]  | ((uint)hi[7]  << 16);
    ph1.x = (uint)hi[8]  | ((uint)hi[9]  << 16); ph1.y = (uint)hi[10] | ((uint)hi[11] << 16);
    ph1.z = (uint)hi[12] | ((uint)hi[13] << 16); ph1.w = (uint)hi[14] | ((uint)hi[15] << 16);
    pl0.x = (uint)lo[0]  | ((uint)lo[1]  << 16); pl0.y = (uint)lo[2]  | ((uint)lo[3]  << 16);
    pl0.z = (uint)lo[4]  | ((uint)lo[5]  << 16); pl0.w = (uint)lo[6]  | ((uint)lo[7]  << 16);
    pl1.x = (uint)lo[8]  | ((uint)lo[9]  << 16); pl1.y = (uint)lo[10] | ((uint)lo[11] << 16);
    pl1.z = (uint)lo[12] | ((uint)lo[13] << 16); pl1.w = (uint)lo[14] | ((uint)lo[15] << 16);
    ((uint4*)(Ohi + obase))[0] = ph0;
    ((uint4*)(Ohi + obase))[1] = ph1;
    ((uint4*)(Olo + obase))[0] = pl0;
    ((uint4*)(Olo + obase))[1] = pl1;
  }
}

// ---------------- BN finalize: PARALLEL (block=channel, wave reduce 400 partials) ----------------
__global__ __launch_bounds__(64) void bn_finalize(const float* __restrict__ psum,
    const float* __restrict__ psq, const float* __restrict__ g,
    const float* __restrict__ bta, float* __restrict__ scale, float* __restrict__ shift)
{
  int c = blockIdx.x;        // 0..127
  int i = threadIdx.x;       // 0..63
  float s = 0.f, q = 0.f;
  for (int r = i; r < 400; r += 64) { s += psum[r*128 + c]; q += psq[r*128 + c]; }
#pragma unroll
  for (int d = 32; d > 0; d >>= 1) { s += __shfl_down(s, d); q += __shfl_down(q, d); }
  if (i == 0) {
    const float invM = 1.f / 51200.f;
    float m  = s * invM;
    float v  = fmaf(q, invM, -m * m);
    float r  = rsqrtf(v + 1e-5f);
    float sc = r * g[c];
    scale[c] = sc;
    shift[c] = fmaf(-m, sc, bta[c]);
  }
}

// ---------------- final BN apply + per-batch mean (fused) ----------------
// One block per batch b; thread d applies scale/shift over n and accumulates mean.
__global__ __launch_bounds__(128) void bn_mean_final(float* __restrict__ hp,
    const float* __restrict__ scale, const float* __restrict__ shift,
    float* __restrict__ mout)
{
  int b = blockIdx.x, d = threadIdx.x;
  float sc = scale[d], sh = shift[d];
  float* p = hp + (size_t)b * N_ * D_ + d;
  float s = 0.f;
  for (int n = 0; n < N_; n++) {
    float v = fmaf(p[n * D_], sc, sh);
    p[n * D_] = v;
    s += v;
  }
  mout[b * D_ + d] = s * (1.f / N_);
}

extern "C" void kernel_launch(void* const* d_in, const int* in_sizes, int n_in,
                              void* d_out, int out_size, void* d_ws, size_t ws_size,
                              hipStream_t stream)
{
  const float* x    = (const float*)d_in[0];
  const float* Wemb = (const float*)d_in[1];
  const float* bemb = (const float*)d_in[2];
  const float* Wq   = (const float*)d_in[3];
  const float* Wk   = (const float*)d_in[4];
  const float* Wv   = (const float*)d_in[5];
  const float* Wo   = (const float*)d_in[6];
  const float* bn1g = (const float*)d_in[7];
  const float* bn1b = (const float*)d_in[8];
  const float* W1   = (const float*)d_in[9];
  const float* b1   = (const float*)d_in[10];
  const float* W2   = (const float*)d_in[11];
  const float* b2   = (const float*)d_in[12];
  const float* bn2g = (const float*)d_in[13];
  const float* bn2b = (const float*)d_in[14];
  float* out = (float*)d_out;

  // rolling pre-BN residual state hp lives in d_out[0:BND]
  float* hp = out;

  char* wsb = (char*)d_ws;
  ushort* h_hi  = (ushort*)wsb;                     // 13,107,200 B
  ushort* h_lo  = (ushort*)(wsb + 13107200);        // 13,107,200 B
  char*   phase = wsb + 26214400;                   // 104,857,600 B union
  float*  qkv   = (float*)phase;                    //   attn: 78,643,200 B fp32
  ushort* hd_hi = (ushort*)(phase + 78643200);      //   attn: 13,107,200 B
  ushort* hd_lo = (ushort*)(phase + 91750400);      //   attn: 13,107,200 B
  ushort* hid_hi = (ushort*)phase;                  //   ffn: 52,428,800 B
  ushort* hid_lo = (ushort*)(phase + 52428800);     //   ffn: 52,428,800 B
  char*   wp    = wsb + 131072000;
  ushort* woT_hi  = (ushort*)wp;                    // 98,304 B
  ushort* woT_lo  = (ushort*)(wp + 98304);          // 98,304 B
  ushort* w2T_hi  = (ushort*)(wp + 196608);         // 393,216 B
  ushort* w2T_lo  = (ushort*)(wp + 589824);         // 393,216 B
  ushort* fqkv_hi = (ushort*)(wp + 983040);         // 98,304 B
  ushort* fqkv_lo = (ushort*)(wp + 1081344);        // 98,304 B
  ushort* fw1_hi  = (ushort*)(wp + 1179648);        // 131,072 B
  ushort* fw1_lo  = (ushort*)(wp + 1310720);        // 131,072 B
  float*  fqkv_b  = (float*)(wp + 1441792);         // 1,536 B
  float*  fw1_b   = (float*)(wp + 1443328);         // 2,048 B
  float*  psum    = (float*)(wp + 1445376);         // 204,800 B
  float*  psq     = (float*)(wp + 1650176);         // 204,800 B
  float*  sc_a    = (float*)(wp + 1854976);
  float*  sh_a    = (float*)(wp + 1855488);
  float*  sc_b    = (float*)(wp + 1856000);
  float*  sh_b    = (float*)(wp + 1856512);

  embed_kernel<<<6400, 256, 0, stream>>>(x, Wemb, bemb, hp, h_hi, h_lo);
  t_wo<<<192, 256, 0, stream>>>(Wo, woT_hi, woT_lo);
  t_w2<<<768, 256, 0, stream>>>(W2, w2T_hi, w2T_lo);
  init_scales<<<1, 128, 0, stream>>>(sc_b, sh_b);

  for (int l = 0; l < L_; l++) {
    // fold BN(prev layer / identity) into QKV weights (parallel, coalesced)
    fold_qkv<<<384, 128, 0, stream>>>(Wq + l*16384, Wk + l*16384, Wv + l*16384,
                                      sc_b, sh_b, fqkv_hi, fqkv_lo, fqkv_b);
    // QKV projection -> qkv fp32 [rows][384]
    gemm_mfma<128, true, false, false, true, false, false><<<dim3(3, 400), 256, 0, stream>>>(
        h_hi, h_lo, fqkv_hi, fqkv_lo, fqkv_b, nullptr, nullptr, nullptr,
        qkv, nullptr, nullptr, nullptr, nullptr, 384);
    // attention -> heads hi/lo
    attn_kernel<<<B_ * H_, 256, 0, stream>>>(qkv, hd_hi, hd_lo);
    // out-proj + BN-folded residual -> hp (h1_pre) fp32 + hi/lo + BN1 stats
    gemm_mfma<128, false, false, true, true, true, true><<<dim3(1, 400), 256, 0, stream>>>(
        hd_hi, hd_lo, woT_hi + l*16384, woT_lo + l*16384, nullptr, hp, sc_b, sh_b,
        hp, h_hi, h_lo, psum, psq, 128);
    bn_finalize<<<128, 64, 0, stream>>>(psum, psq, bn1g + l*128, bn1b + l*128, sc_a, sh_a);
    // fold BN1 into W1 (parallel, coalesced)
    fold_w1<<<512, 128, 0, stream>>>(W1 + l*65536, b1 + l*512, sc_a, sh_a, fw1_hi, fw1_lo, fw1_b);
    // FFN1 + folded bias + relu -> hidden hi/lo
    gemm_mfma<128, true, true, false, false, true, false><<<dim3(4, 400), 256, 0, stream>>>(
        h_hi, h_lo, fw1_hi, fw1_lo, fw1_b, nullptr, nullptr, nullptr,
        nullptr, hid_hi, hid_lo, nullptr, nullptr, 512);
    // FFN2 + bias + BN1-folded residual -> hp (h2_pre) fp32 + hi/lo + BN2 stats
    gemm_mfma<512, true, false, true, true, true, true><<<dim3(1, 400), 256, 0, stream>>>(
        hid_hi, hid_lo, w2T_hi + l*65536, w2T_lo + l*65536, b2 + l*128, hp, sc_a, sh_a,
        hp, h_hi, h_lo, psum, psq, 128);
    bn_finalize<<<128, 64, 0, stream>>>(psum, psq, bn2g + l*128, bn2b + l*128, sc_b, sh_b);
  }

  bn_mean_final<<<B_, 128, 0, stream>>>(hp, sc_b, sh_b, out + BND);
}